// Round 1
// baseline (956.968 us; speedup 1.0000x reference)
//
#include <hip/hip_runtime.h>
#include <hip/hip_bf16.h>
#include <cstdint>

#define B_DIM 2
#define S_LEN 2048
#define HID 4096
#define NH 32
#define NKV 8
#define HD 128
#define QSZ (NH * HD)          // 4096
#define KVSZ (NKV * HD)        // 1024
#define QKVW (QSZ + 2 * KVSZ)  // 6144
#define SCALING 0.08838834764831845f

typedef __bf16 bf16;
typedef __bf16 bf16x4 __attribute__((ext_vector_type(4)));
typedef __bf16 bf16x8 __attribute__((ext_vector_type(8)));
typedef float floatx4 __attribute__((ext_vector_type(4)));

typedef __attribute__((address_space(1))) void GV;
typedef __attribute__((address_space(3))) void SV;

// ---------------- f32 -> bf16 convert ----------------
__global__ __launch_bounds__(256) void cvt_f32_bf16(const float* __restrict__ in,
                                                    bf16* __restrict__ out, int n) {
    int n4 = n >> 2;
    int stride = gridDim.x * blockDim.x;
    for (int i = blockIdx.x * blockDim.x + threadIdx.x; i < n4; i += stride) {
        float4 v = ((const float4*)in)[i];
        bf16x4 o;
        o[0] = (bf16)v.x; o[1] = (bf16)v.y; o[2] = (bf16)v.z; o[3] = (bf16)v.w;
        ((bf16x4*)out)[i] = o;
    }
}

// ---------------- GEMM C[m,n] = sum_k A[m,k] * B[n,k]  (m97 structure) ----------------
// A: M x K row-major bf16, B: N x K row-major bf16, C: M x N row-major OutT
template <typename OutT>
__global__ __launch_bounds__(256) void gemm_bt(const bf16* __restrict__ A,
                                               const bf16* __restrict__ Bm,
                                               OutT* __restrict__ C, int M, int N, int K) {
    __shared__ __align__(16) bf16 As[128 * 32];
    __shared__ __align__(16) bf16 Bs[128 * 32];
    int tiles_n = N >> 7;
    int bm = blockIdx.x / tiles_n, bn = blockIdx.x % tiles_n;
    int tid = threadIdx.x, lane = tid & 63, w = tid >> 6;
    int l15 = lane & 15, lg = lane >> 4;
    int wr = (w >> 1) * 64, wc = (w & 1) * 64;
    floatx4 acc[4][4] = {};
    const bf16* Ab = A + (size_t)bm * 128 * K;
    const bf16* Bb = Bm + (size_t)bn * 128 * K;
    for (int k0 = 0; k0 < K; k0 += 32) {
#pragma unroll
        for (int c = 0; c < 2; ++c) {
            int e = c * 2048 + tid * 8;
            int r = e >> 5, cl = e & 31;
            __builtin_amdgcn_global_load_lds((GV*)(Ab + (size_t)r * K + k0 + cl),
                                             (SV*)(As + e), 16, 0, 0);
            __builtin_amdgcn_global_load_lds((GV*)(Bb + (size_t)r * K + k0 + cl),
                                             (SV*)(Bs + e), 16, 0, 0);
        }
        __syncthreads();
        bf16x8 af[4], bfr[4];
#pragma unroll
        for (int i = 0; i < 4; ++i) {
            af[i]  = *(const bf16x8*)(As + (wr + i * 16 + l15) * 32 + lg * 8);
            bfr[i] = *(const bf16x8*)(Bs + (wc + i * 16 + l15) * 32 + lg * 8);
        }
#pragma unroll
        for (int i = 0; i < 4; ++i)
#pragma unroll
            for (int j = 0; j < 4; ++j)
                acc[i][j] = __builtin_amdgcn_mfma_f32_16x16x32_bf16(af[i], bfr[j], acc[i][j], 0, 0, 0);
        __syncthreads();
    }
    int brow = bm * 128 + wr, bcol = bn * 128 + wc;
#pragma unroll
    for (int i = 0; i < 4; ++i)
#pragma unroll
        for (int j = 0; j < 4; ++j) {
            int col = bcol + j * 16 + l15;
#pragma unroll
            for (int r = 0; r < 4; ++r) {
                int row = brow + i * 16 + lg * 4 + r;
                C[(size_t)row * N + col] = (OutT)acc[i][j][r];
            }
        }
}

// ---------------- RoPE + reshape: qkv[B*S][6144] -> Q[B,NH,S,HD], K[B,NKV,S,HD] ----------------
__global__ __launch_bounds__(256) void rope_qk(const bf16* __restrict__ qkv,
                                               const float* __restrict__ cosp,
                                               const float* __restrict__ sinp,
                                               bf16* __restrict__ Q, bf16* __restrict__ K) {
    int bs = blockIdx.x;  // b*S + s
    int b = bs >> 11, s = bs & (S_LEN - 1);
    const bf16* row = qkv + (size_t)bs * QKVW;
    const float* cr = cosp + (size_t)bs * HD;
    const float* sr = sinp + (size_t)bs * HD;
    int t = threadIdx.x;
    int h = t >> 3, d0 = (t & 7) * 8;
    {
        bf16x8 x1 = *(const bf16x8*)(row + h * HD + d0);
        bf16x8 x2 = *(const bf16x8*)(row + h * HD + 64 + d0);
        bf16x8 o1, o2;
#pragma unroll
        for (int j = 0; j < 8; ++j) {
            float a = (float)x1[j], bv = (float)x2[j];
            o1[j] = (bf16)(a * cr[d0 + j] - bv * sr[d0 + j]);
            o2[j] = (bf16)(bv * cr[64 + d0 + j] + a * sr[64 + d0 + j]);
        }
        size_t qb = (((size_t)b * NH + h) * S_LEN + s) * HD;
        *(bf16x8*)(Q + qb + d0) = o1;
        *(bf16x8*)(Q + qb + 64 + d0) = o2;
    }
    if (t < 64) {
        int kh = t >> 3;
        bf16x8 x1 = *(const bf16x8*)(row + QSZ + kh * HD + d0);
        bf16x8 x2 = *(const bf16x8*)(row + QSZ + kh * HD + 64 + d0);
        bf16x8 o1, o2;
#pragma unroll
        for (int j = 0; j < 8; ++j) {
            float a = (float)x1[j], bv = (float)x2[j];
            o1[j] = (bf16)(a * cr[d0 + j] - bv * sr[d0 + j]);
            o2[j] = (bf16)(bv * cr[64 + d0 + j] + a * sr[64 + d0 + j]);
        }
        size_t kb = (((size_t)b * NKV + kh) * S_LEN + s) * HD;
        *(bf16x8*)(K + kb + d0) = o1;
        *(bf16x8*)(K + kb + 64 + d0) = o2;
    }
}

// ---------------- V transpose: qkv v-slice -> Vt[B,NKV,HD,S] ----------------
__global__ __launch_bounds__(256) void v_transpose(const bf16* __restrict__ qkv,
                                                   bf16* __restrict__ Vt) {
    // grid: bk(16) x st(32) x dt(2)
    int bid = blockIdx.x;
    int dt = bid & 1, st = (bid >> 1) & 31, bk = bid >> 6;
    int b = bk >> 3, kv = bk & 7;
    __shared__ __align__(16) bf16 tile[64][72];
    int t = threadIdx.x;
#pragma unroll
    for (int it = 0; it < 2; ++it) {
        int i = it * 32 + (t >> 3);          // s within tile
        int j8 = (t & 7) * 8;                // d within tile
        bf16x8 v = *(const bf16x8*)(qkv + ((size_t)(b * S_LEN + st * 64 + i)) * QKVW +
                                    QSZ + KVSZ + kv * HD + dt * 64 + j8);
        *(bf16x8*)&tile[i][j8] = v;
    }
    __syncthreads();
    int dl = t >> 2, s8 = (t & 3) * 16;
    bf16x8 o0, o1;
#pragma unroll
    for (int u = 0; u < 8; ++u) { o0[u] = tile[s8 + u][dl]; o1[u] = tile[s8 + 8 + u][dl]; }
    size_t ob = (((size_t)b * NKV + kv) * HD + dt * 64 + dl) * S_LEN + st * 64 + s8;
    *(bf16x8*)(Vt + ob) = o0;
    *(bf16x8*)(Vt + ob + 8) = o1;
}

// ---------------- causal GQA flash attention ----------------
// Q[B,NH,S,HD], K[B,NKV,S,HD], Vt[B,NKV,HD,S] -> O[B,S,NH,HD]
__global__ __launch_bounds__(256) void attn_fwd(const bf16* __restrict__ Q,
                                                const bf16* __restrict__ K,
                                                const bf16* __restrict__ Vt,
                                                bf16* __restrict__ O) {
    __shared__ __align__(16) bf16 Ks[64][136];
    __shared__ __align__(16) bf16 Vs[128][72];
    __shared__ __align__(16) bf16 Ps[4][16][72];
    int bid = blockIdx.x;
    int qt = bid & 31, bh = bid >> 5, h = bh & 31, b = bh >> 5;
    int kvh = h >> 2;  // GROUPS = 4
    int tid = threadIdx.x, lane = tid & 63, w = tid >> 6;
    int l15 = lane & 15, lg = lane >> 4;
    int q0 = qt * 64;
    const bf16* Qb = Q + ((size_t)(b * NH + h) * S_LEN) * HD;
    const bf16* Kb = K + ((size_t)(b * NKV + kvh) * S_LEN) * HD;
    const bf16* Vb = Vt + ((size_t)(b * NKV + kvh) * HD) * S_LEN;
    int qrow = q0 + w * 16 + l15;
    bf16x8 qf[4];
#pragma unroll
    for (int ks = 0; ks < 4; ++ks)
        qf[ks] = *(const bf16x8*)(Qb + (size_t)qrow * HD + ks * 32 + lg * 8);
    floatx4 accO[8] = {};
    float m_run[4], l_run[4];
#pragma unroll
    for (int r = 0; r < 4; ++r) { m_run[r] = -1e30f; l_run[r] = 0.f; }

    for (int t = 0; t <= qt; ++t) {
        int kv0 = t * 64;
#pragma unroll
        for (int it = 0; it < 4; ++it) {
            int e = it * 2048 + tid * 8;
            int rk = e >> 7, ck = e & 127;
            *(bf16x8*)&Ks[rk][ck] = *(const bf16x8*)(Kb + (size_t)(kv0 + rk) * HD + ck);
            int rv = e >> 6, cv = e & 63;
            *(bf16x8*)&Vs[rv][cv] = *(const bf16x8*)(Vb + (size_t)rv * S_LEN + kv0 + cv);
        }
        __syncthreads();
        floatx4 sc[4];
#pragma unroll
        for (int ng = 0; ng < 4; ++ng) {
            floatx4 a = {};
#pragma unroll
            for (int ks = 0; ks < 4; ++ks) {
                bf16x8 kf = *(const bf16x8*)&Ks[ng * 16 + l15][ks * 32 + lg * 8];
                a = __builtin_amdgcn_mfma_f32_16x16x32_bf16(qf[ks], kf, a, 0, 0, 0);
            }
            sc[ng] = a;
        }
        bool diag = (t == qt);
        float rmax[4] = {-1e30f, -1e30f, -1e30f, -1e30f};
#pragma unroll
        for (int ng = 0; ng < 4; ++ng)
#pragma unroll
            for (int r = 0; r < 4; ++r) {
                float sv = sc[ng][r] * SCALING;
                if (diag && (kv0 + ng * 16 + l15 > q0 + w * 16 + lg * 4 + r)) sv = -1e30f;
                sc[ng][r] = sv;
                rmax[r] = fmaxf(rmax[r], sv);
            }
#pragma unroll
        for (int m = 1; m <= 8; m <<= 1)
#pragma unroll
            for (int r = 0; r < 4; ++r)
                rmax[r] = fmaxf(rmax[r], __shfl_xor(rmax[r], m));
        float corr[4], rsum[4];
#pragma unroll
        for (int r = 0; r < 4; ++r) {
            float mn = fmaxf(m_run[r], rmax[r]);
            corr[r] = __expf(m_run[r] - mn);
            m_run[r] = mn;
            rsum[r] = 0.f;
        }
#pragma unroll
        for (int ng = 0; ng < 4; ++ng)
#pragma unroll
            for (int r = 0; r < 4; ++r) {
                float p = __expf(sc[ng][r] - m_run[r]);
                sc[ng][r] = p;
                rsum[r] += p;
            }
#pragma unroll
        for (int m = 1; m <= 8; m <<= 1)
#pragma unroll
            for (int r = 0; r < 4; ++r)
                rsum[r] += __shfl_xor(rsum[r], m);
#pragma unroll
        for (int r = 0; r < 4; ++r) l_run[r] = l_run[r] * corr[r] + rsum[r];
#pragma unroll
        for (int g = 0; g < 8; ++g)
#pragma unroll
            for (int r = 0; r < 4; ++r) accO[g][r] *= corr[r];
#pragma unroll
        for (int ng = 0; ng < 4; ++ng)
#pragma unroll
            for (int r = 0; r < 4; ++r)
                Ps[w][lg * 4 + r][ng * 16 + l15] = (bf16)sc[ng][r];
        asm volatile("s_waitcnt lgkmcnt(0)" ::: "memory");
#pragma unroll
        for (int g = 0; g < 8; ++g)
#pragma unroll
            for (int ks = 0; ks < 2; ++ks) {
                bf16x8 pf = *(const bf16x8*)&Ps[w][l15][ks * 32 + lg * 8];
                bf16x8 vf = *(const bf16x8*)&Vs[g * 16 + l15][ks * 32 + lg * 8];
                accO[g] = __builtin_amdgcn_mfma_f32_16x16x32_bf16(pf, vf, accO[g], 0, 0, 0);
            }
        __syncthreads();
    }
#pragma unroll
    for (int r = 0; r < 4; ++r) {
        float inv = 1.f / l_run[r];
        int qr = q0 + w * 16 + lg * 4 + r;
        size_t ob = ((size_t)(b * S_LEN + qr) * NH + h) * HD;
#pragma unroll
        for (int g = 0; g < 8; ++g)
            O[ob + g * 16 + l15] = (bf16)(accO[g][r] * inv);
    }
}

extern "C" void kernel_launch(void* const* d_in, const int* in_sizes, int n_in,
                              void* d_out, int out_size, void* d_ws, size_t ws_size,
                              hipStream_t stream) {
    const float* hs   = (const float*)d_in[0];
    const float* cosp = (const float*)d_in[1];
    const float* sinp = (const float*)d_in[2];
    const float* wqkv = (const float*)d_in[3];
    const float* wo   = (const float*)d_in[4];
    float* out = (float*)d_out;

    char* ws = (char*)d_ws;
    size_t off = 0;
    auto alloc = [&](size_t bytes) {
        char* p = ws + off;
        off += (bytes + 255) & ~(size_t)255;
        return p;
    };
    const size_t n_hs = (size_t)B_DIM * S_LEN * HID;    // 16.8M
    const size_t n_wqkv = (size_t)QKVW * HID;           // 25.2M
    const size_t n_wo = (size_t)HID * QSZ;              // 16.8M
    const size_t n_qkv = (size_t)B_DIM * S_LEN * QKVW;  // 25.2M

    bf16* hs_b   = (bf16*)alloc(n_hs * 2);
    bf16* wqkv_b = (bf16*)alloc(n_wqkv * 2);
    bf16* wo_b   = (bf16*)alloc(n_wo * 2);
    bf16* qkv_b  = (bf16*)alloc(n_qkv * 2);
    bf16* Qb  = (bf16*)alloc((size_t)B_DIM * NH * S_LEN * HD * 2);
    bf16* Kb  = (bf16*)alloc((size_t)B_DIM * NKV * S_LEN * HD * 2);
    bf16* Vtb = (bf16*)alloc((size_t)B_DIM * NKV * HD * S_LEN * 2);
    bf16* attn_b = hs_b;  // hs_b is dead after gemm1 — reuse for attention output

    cvt_f32_bf16<<<1024, 256, 0, stream>>>(hs, hs_b, (int)n_hs);
    cvt_f32_bf16<<<1024, 256, 0, stream>>>(wqkv, wqkv_b, (int)n_wqkv);
    cvt_f32_bf16<<<1024, 256, 0, stream>>>(wo, wo_b, (int)n_wo);

    gemm_bt<bf16><<<(4096 / 128) * (6144 / 128), 256, 0, stream>>>(
        hs_b, wqkv_b, qkv_b, B_DIM * S_LEN, QKVW, HID);

    rope_qk<<<B_DIM * S_LEN, 256, 0, stream>>>(qkv_b, cosp, sinp, Qb, Kb);
    v_transpose<<<B_DIM * NKV * (S_LEN / 64) * (HD / 64), 256, 0, stream>>>(qkv_b, Vtb);

    attn_fwd<<<B_DIM * NH * (S_LEN / 64), 256, 0, stream>>>(Qb, Kb, Vtb, attn_b);

    gemm_bt<float><<<(4096 / 128) * (4096 / 128), 256, 0, stream>>>(
        attn_b, wo_b, out, B_DIM * S_LEN, HID, HID);
}

// Round 2
// 714.414 us; speedup vs baseline: 1.3395x; 1.3395x over previous
//
#include <hip/hip_runtime.h>
#include <hip/hip_bf16.h>
#include <cstdint>

#define B_DIM 2
#define S_LEN 2048
#define HID 4096
#define NH 32
#define NKV 8
#define HD 128
#define QSZ (NH * HD)          // 4096
#define KVSZ (NKV * HD)        // 1024
#define QKVW (QSZ + 2 * KVSZ)  // 6144
#define SCALING 0.08838834764831845f

typedef __bf16 bf16;
typedef __bf16 bf16x4 __attribute__((ext_vector_type(4)));
typedef __bf16 bf16x8 __attribute__((ext_vector_type(8)));
typedef float floatx4 __attribute__((ext_vector_type(4)));

typedef __attribute__((address_space(1))) void GV;
typedef __attribute__((address_space(3))) void SV;

// ---------------- f32 -> bf16 convert ----------------
__global__ __launch_bounds__(256) void cvt_f32_bf16(const float* __restrict__ in,
                                                    bf16* __restrict__ out, int n) {
    int n4 = n >> 2;
    int stride = gridDim.x * blockDim.x;
    for (int i = blockIdx.x * blockDim.x + threadIdx.x; i < n4; i += stride) {
        float4 v = ((const float4*)in)[i];
        bf16x4 o;
        o[0] = (bf16)v.x; o[1] = (bf16)v.y; o[2] = (bf16)v.z; o[3] = (bf16)v.w;
        ((bf16x4*)out)[i] = o;
    }
}

// ---------------- GEMM C[m,n] = sum_k A[m,k] * B[n,k]  (m97 structure) ----------------
template <typename OutT>
__global__ __launch_bounds__(256) void gemm_bt(const bf16* __restrict__ A,
                                               const bf16* __restrict__ Bm,
                                               OutT* __restrict__ C, int M, int N, int K) {
    __shared__ __align__(16) bf16 As[128 * 32];
    __shared__ __align__(16) bf16 Bs[128 * 32];
    int tiles_n = N >> 7;
    int bm = blockIdx.x / tiles_n, bn = blockIdx.x % tiles_n;
    int tid = threadIdx.x, lane = tid & 63, w = tid >> 6;
    int l15 = lane & 15, lg = lane >> 4;
    int wr = (w >> 1) * 64, wc = (w & 1) * 64;
    floatx4 acc[4][4] = {};
    const bf16* Ab = A + (size_t)bm * 128 * K;
    const bf16* Bb = Bm + (size_t)bn * 128 * K;
    for (int k0 = 0; k0 < K; k0 += 32) {
#pragma unroll
        for (int c = 0; c < 2; ++c) {
            int e = c * 2048 + tid * 8;
            int r = e >> 5, cl = e & 31;
            __builtin_amdgcn_global_load_lds((GV*)(Ab + (size_t)r * K + k0 + cl),
                                             (SV*)(As + e), 16, 0, 0);
            __builtin_amdgcn_global_load_lds((GV*)(Bb + (size_t)r * K + k0 + cl),
                                             (SV*)(Bs + e), 16, 0, 0);
        }
        __syncthreads();
        bf16x8 af[4], bfr[4];
#pragma unroll
        for (int i = 0; i < 4; ++i) {
            af[i]  = *(const bf16x8*)(As + (wr + i * 16 + l15) * 32 + lg * 8);
            bfr[i] = *(const bf16x8*)(Bs + (wc + i * 16 + l15) * 32 + lg * 8);
        }
#pragma unroll
        for (int i = 0; i < 4; ++i)
#pragma unroll
            for (int j = 0; j < 4; ++j)
                acc[i][j] = __builtin_amdgcn_mfma_f32_16x16x32_bf16(af[i], bfr[j], acc[i][j], 0, 0, 0);
        __syncthreads();
    }
    int brow = bm * 128 + wr, bcol = bn * 128 + wc;
#pragma unroll
    for (int i = 0; i < 4; ++i)
#pragma unroll
        for (int j = 0; j < 4; ++j) {
            int col = bcol + j * 16 + l15;
#pragma unroll
            for (int r = 0; r < 4; ++r) {
                int row = brow + i * 16 + lg * 4 + r;
                C[(size_t)row * N + col] = (OutT)acc[i][j][r];
            }
        }
}

// ---------------- RoPE + reshape (Q pre-scaled by SCALING) ----------------
__global__ __launch_bounds__(256) void rope_qk(const bf16* __restrict__ qkv,
                                               const float* __restrict__ cosp,
                                               const float* __restrict__ sinp,
                                               bf16* __restrict__ Q, bf16* __restrict__ K) {
    int bs = blockIdx.x;
    int b = bs >> 11, s = bs & (S_LEN - 1);
    const bf16* row = qkv + (size_t)bs * QKVW;
    const float* cr = cosp + (size_t)bs * HD;
    const float* sr = sinp + (size_t)bs * HD;
    int t = threadIdx.x;
    int h = t >> 3, d0 = (t & 7) * 8;
    {
        bf16x8 x1 = *(const bf16x8*)(row + h * HD + d0);
        bf16x8 x2 = *(const bf16x8*)(row + h * HD + 64 + d0);
        bf16x8 o1, o2;
#pragma unroll
        for (int j = 0; j < 8; ++j) {
            float a = (float)x1[j], bv = (float)x2[j];
            o1[j] = (bf16)((a * cr[d0 + j] - bv * sr[d0 + j]) * SCALING);
            o2[j] = (bf16)((bv * cr[64 + d0 + j] + a * sr[64 + d0 + j]) * SCALING);
        }
        size_t qb = (((size_t)b * NH + h) * S_LEN + s) * HD;
        *(bf16x8*)(Q + qb + d0) = o1;
        *(bf16x8*)(Q + qb + 64 + d0) = o2;
    }
    if (t < 64) {
        int kh = t >> 3;
        bf16x8 x1 = *(const bf16x8*)(row + QSZ + kh * HD + d0);
        bf16x8 x2 = *(const bf16x8*)(row + QSZ + kh * HD + 64 + d0);
        bf16x8 o1, o2;
#pragma unroll
        for (int j = 0; j < 8; ++j) {
            float a = (float)x1[j], bv = (float)x2[j];
            o1[j] = (bf16)(a * cr[d0 + j] - bv * sr[d0 + j]);
            o2[j] = (bf16)(bv * cr[64 + d0 + j] + a * sr[64 + d0 + j]);
        }
        size_t kb = (((size_t)b * NKV + kh) * S_LEN + s) * HD;
        *(bf16x8*)(K + kb + d0) = o1;
        *(bf16x8*)(K + kb + 64 + d0) = o2;
    }
}

// ---------------- V transpose: qkv v-slice -> Vt[B,NKV,HD,S] ----------------
__global__ __launch_bounds__(256) void v_transpose(const bf16* __restrict__ qkv,
                                                   bf16* __restrict__ Vt) {
    int bid = blockIdx.x;
    int dt = bid & 1, st = (bid >> 1) & 31, bk = bid >> 6;
    int b = bk >> 3, kv = bk & 7;
    __shared__ __align__(16) bf16 tile[64][72];
    int t = threadIdx.x;
#pragma unroll
    for (int it = 0; it < 2; ++it) {
        int i = it * 32 + (t >> 3);
        int j8 = (t & 7) * 8;
        bf16x8 v = *(const bf16x8*)(qkv + ((size_t)(b * S_LEN + st * 64 + i)) * QKVW +
                                    QSZ + KVSZ + kv * HD + dt * 64 + j8);
        *(bf16x8*)&tile[i][j8] = v;
    }
    __syncthreads();
    int dl = t >> 2, s8 = (t & 3) * 16;
    bf16x8 o0, o1;
#pragma unroll
    for (int u = 0; u < 8; ++u) { o0[u] = tile[s8 + u][dl]; o1[u] = tile[s8 + 8 + u][dl]; }
    size_t ob = (((size_t)b * NKV + kv) * HD + dt * 64 + dl) * S_LEN + st * 64 + s8;
    *(bf16x8*)(Vt + ob) = o0;
    *(bf16x8*)(Vt + ob + 8) = o1;
}

// ---------------- causal GQA flash attention (swapped-QK, dbuf, swizzled LDS) ----------
// Q[B,NH,S,HD] (pre-scaled), K[B,NKV,S,HD], Vt[B,NKV,HD,S] -> O[B,S,NH,HD]
// block: 256 thr = 4 waves, QBLK=128 (32 q-rows/wave, 2 sub-blocks of 16), KVBLK=64.
__global__ __launch_bounds__(256, 2) void attn_fwd(const bf16* __restrict__ Q,
                                                   const bf16* __restrict__ K,
                                                   const bf16* __restrict__ Vt,
                                                   bf16* __restrict__ O) {
    __shared__ __align__(16) bf16 Ks[2][64 * 128];   // 32 KB (rows=kv, 256B, swizzled)
    __shared__ __align__(16) bf16 Vs[2][128 * 64];   // 32 KB (rows=d, 128B, swizzled)
    __shared__ __align__(16) bf16 Ps[4][32 * 64];    // 16 KB per-wave P (rows=q, 128B, swizzled)

    int bid = blockIdx.x;
    int qt = bid & 15, bh = bid >> 4, h = bh & 31, b = bh >> 5;
    int kvh = h >> 2;
    int tid = threadIdx.x, lane = tid & 63, w = tid >> 6;
    int l15 = lane & 15, lg = lane >> 4, l7 = l15 & 7, lg4 = lg * 4;
    int q0 = qt * 128;
    int qbw = q0 + w * 32;

    const bf16* Qb = Q + ((size_t)(b * NH + h) * S_LEN) * HD;
    const bf16* Kb = K + ((size_t)(b * NKV + kvh) * S_LEN) * HD;
    const bf16* Vb = Vt + ((size_t)(b * NKV + kvh) * HD) * S_LEN;

    // Q fragments in registers: qf[i][ks], lane l15 = q col, lg*8 = d chunk
    bf16x8 qf[2][4];
#pragma unroll
    for (int i = 0; i < 2; ++i)
#pragma unroll
        for (int ks = 0; ks < 4; ++ks)
            qf[i][ks] = *(const bf16x8*)(Qb + (size_t)(qbw + i * 16 + l15) * HD + ks * 32 + lg * 8);

    floatx4 accO[2][8] = {};
    float m_run[2] = {-1e30f, -1e30f}, l_run[2] = {0.f, 0.f};

    char* Pc = (char*)Ps[w];
    int nt = 2 * qt + 2;

    auto stage = [&](int buf, int t) {
        int kv0 = t * 64;
#pragma unroll
        for (int it = 0; it < 4; ++it) {
            int o = it * 4096 + tid * 16;
            int r = o >> 8, pb = (o >> 4) & 15;
            int lb = pb ^ (r & 7);
            __builtin_amdgcn_global_load_lds((GV*)(Kb + (size_t)(kv0 + r) * HD + lb * 8),
                                             (SV*)((char*)Ks[buf] + o), 16, 0, 0);
        }
#pragma unroll
        for (int it = 0; it < 4; ++it) {
            int o = it * 4096 + tid * 16;
            int d = o >> 7, pb = (o >> 4) & 7;
            int lb = pb ^ (d & 7);
            __builtin_amdgcn_global_load_lds((GV*)(Vb + (size_t)d * S_LEN + kv0 + lb * 8),
                                             (SV*)((char*)Vs[buf] + o), 16, 0, 0);
        }
    };

    stage(0, 0);
    __syncthreads();

    for (int t = 0; t < nt; ++t) {
        int cur = t & 1;
        if (t + 1 < nt) stage(cur ^ 1, t + 1);
        int kv0 = t * 64;
        const char* Kc = (const char*)Ks[cur];
        const char* Vc = (const char*)Vs[cur];

        // ---- QK^T swapped: S^T[kv][q] = mfma(K, Q) ----
        floatx4 s[2][4] = {};
#pragma unroll
        for (int nm = 0; nm < 4; ++nm)
#pragma unroll
            for (int ks = 0; ks < 4; ++ks) {
                bf16x8 kf = *(const bf16x8*)(Kc + (nm * 16 + l15) * 256 +
                                             ((((ks << 2) | lg) ^ l7) << 4));
                s[0][nm] = __builtin_amdgcn_mfma_f32_16x16x32_bf16(kf, qf[0][ks], s[0][nm], 0, 0, 0);
                s[1][nm] = __builtin_amdgcn_mfma_f32_16x16x32_bf16(kf, qf[1][ks], s[1][nm], 0, 0, 0);
            }

        // ---- softmax (per lane: one q col per sub-block) ----
#pragma unroll
        for (int i = 0; i < 2; ++i) {
            if (kv0 + 63 > qbw + i * 16) {  // wave-uniform mask branch
                int qg = qbw + i * 16 + l15;
#pragma unroll
                for (int nm = 0; nm < 4; ++nm)
#pragma unroll
                    for (int r = 0; r < 4; ++r)
                        if (kv0 + nm * 16 + lg4 + r > qg) s[i][nm][r] = -1e30f;
            }
            float mx = -1e30f;
#pragma unroll
            for (int nm = 0; nm < 4; ++nm)
#pragma unroll
                for (int r = 0; r < 4; ++r) mx = fmaxf(mx, s[i][nm][r]);
            mx = fmaxf(mx, __shfl_xor(mx, 16));
            mx = fmaxf(mx, __shfl_xor(mx, 32));
            float mn = fmaxf(m_run[i], mx);
            float corr = __expf(m_run[i] - mn);
            m_run[i] = mn;
            float sum = 0.f;
#pragma unroll
            for (int nm = 0; nm < 4; ++nm) {
                bf16x4 pk;
#pragma unroll
                for (int r = 0; r < 4; ++r) {
                    float p = __expf(s[i][nm][r] - mn);
                    sum += p;
                    pk[r] = (bf16)p;
                }
                *(bf16x4*)(Pc + (i * 16 + l15) * 128 +
                           ((((nm << 1) | (lg >> 1)) ^ l7) << 4) + ((lg & 1) << 3)) = pk;
            }
            sum += __shfl_xor(sum, 16);
            sum += __shfl_xor(sum, 32);
            l_run[i] = l_run[i] * corr + sum;
#pragma unroll
            for (int r = 0; r < 4; ++r) {
                float cr = __shfl(corr, lg4 + r);
#pragma unroll
                for (int g = 0; g < 8; ++g) accO[i][g][r] *= cr;
            }
        }
        asm volatile("s_waitcnt lgkmcnt(0)" ::: "memory");

        // ---- PV: O += P @ V ----
        bf16x8 pf[2][2];
#pragma unroll
        for (int i = 0; i < 2; ++i)
#pragma unroll
            for (int ks = 0; ks < 2; ++ks)
                pf[i][ks] = *(const bf16x8*)(Pc + (i * 16 + l15) * 128 +
                                             ((((ks << 2) | lg) ^ l7) << 4));
#pragma unroll
        for (int g = 0; g < 8; ++g)
#pragma unroll
            for (int ks = 0; ks < 2; ++ks) {
                bf16x8 vf = *(const bf16x8*)(Vc + (g * 16 + l15) * 128 +
                                             ((((ks << 2) | lg) ^ l7) << 4));
                accO[0][g] = __builtin_amdgcn_mfma_f32_16x16x32_bf16(pf[0][ks], vf, accO[0][g], 0, 0, 0);
                accO[1][g] = __builtin_amdgcn_mfma_f32_16x16x32_bf16(pf[1][ks], vf, accO[1][g], 0, 0, 0);
            }
        __syncthreads();
    }

    // ---- epilogue ----
#pragma unroll
    for (int i = 0; i < 2; ++i) {
        float inv = 1.f / l_run[i];
#pragma unroll
        for (int r = 0; r < 4; ++r) {
            float vinv = __shfl(inv, lg4 + r);
            int qg = qbw + i * 16 + lg4 + r;
            size_t ob = ((size_t)(b * S_LEN + qg) * NH + h) * HD;
#pragma unroll
            for (int g = 0; g < 8; ++g)
                O[ob + g * 16 + l15] = (bf16)(accO[i][g][r] * vinv);
        }
    }
}

extern "C" void kernel_launch(void* const* d_in, const int* in_sizes, int n_in,
                              void* d_out, int out_size, void* d_ws, size_t ws_size,
                              hipStream_t stream) {
    const float* hs   = (const float*)d_in[0];
    const float* cosp = (const float*)d_in[1];
    const float* sinp = (const float*)d_in[2];
    const float* wqkv = (const float*)d_in[3];
    const float* wo   = (const float*)d_in[4];
    float* out = (float*)d_out;

    char* ws = (char*)d_ws;
    size_t off = 0;
    auto alloc = [&](size_t bytes) {
        char* p = ws + off;
        off += (bytes + 255) & ~(size_t)255;
        return p;
    };
    const size_t n_hs = (size_t)B_DIM * S_LEN * HID;
    const size_t n_wqkv = (size_t)QKVW * HID;
    const size_t n_wo = (size_t)HID * QSZ;
    const size_t n_qkv = (size_t)B_DIM * S_LEN * QKVW;

    bf16* hs_b   = (bf16*)alloc(n_hs * 2);
    bf16* wqkv_b = (bf16*)alloc(n_wqkv * 2);
    bf16* wo_b   = (bf16*)alloc(n_wo * 2);
    bf16* qkv_b  = (bf16*)alloc(n_qkv * 2);
    bf16* Qb  = (bf16*)alloc((size_t)B_DIM * NH * S_LEN * HD * 2);
    bf16* Kb  = (bf16*)alloc((size_t)B_DIM * NKV * S_LEN * HD * 2);
    bf16* Vtb = (bf16*)alloc((size_t)B_DIM * NKV * HD * S_LEN * 2);
    bf16* attn_b = hs_b;  // hs_b dead after gemm1

    cvt_f32_bf16<<<1024, 256, 0, stream>>>(hs, hs_b, (int)n_hs);
    cvt_f32_bf16<<<1024, 256, 0, stream>>>(wqkv, wqkv_b, (int)n_wqkv);
    cvt_f32_bf16<<<1024, 256, 0, stream>>>(wo, wo_b, (int)n_wo);

    gemm_bt<bf16><<<(4096 / 128) * (6144 / 128), 256, 0, stream>>>(
        hs_b, wqkv_b, qkv_b, B_DIM * S_LEN, QKVW, HID);

    rope_qk<<<B_DIM * S_LEN, 256, 0, stream>>>(qkv_b, cosp, sinp, Qb, Kb);
    v_transpose<<<B_DIM * NKV * (S_LEN / 64) * (HD / 64), 256, 0, stream>>>(qkv_b, Vtb);

    attn_fwd<<<B_DIM * NH * (S_LEN / 128), 256, 0, stream>>>(Qb, Kb, Vtb, attn_b);

    gemm_bt<float><<<(4096 / 128) * (4096 / 128), 256, 0, stream>>>(
        attn_b, wo_b, out, B_DIM * S_LEN, HID, HID);
}

// Round 3
// 619.918 us; speedup vs baseline: 1.5437x; 1.1524x over previous
//
#include <hip/hip_runtime.h>
#include <hip/hip_bf16.h>
#include <cstdint>

#define B_DIM 2
#define S_LEN 2048
#define HID 4096
#define NH 32
#define NKV 8
#define HD 128
#define QSZ (NH * HD)          // 4096
#define KVSZ (NKV * HD)        // 1024
#define QKVW (QSZ + 2 * KVSZ)  // 6144
#define SCALING 0.08838834764831845f

typedef __bf16 bf16;
typedef __bf16 bf16x4 __attribute__((ext_vector_type(4)));
typedef __bf16 bf16x8 __attribute__((ext_vector_type(8)));
typedef float floatx4 __attribute__((ext_vector_type(4)));

typedef __attribute__((address_space(1))) void GV;
typedef __attribute__((address_space(3))) void SV;

#define BAR() __builtin_amdgcn_s_barrier()

// ---------------- f32 -> bf16 convert ----------------
__global__ __launch_bounds__(256) void cvt_f32_bf16(const float* __restrict__ in,
                                                    bf16* __restrict__ out, int n) {
    int n4 = n >> 2;
    int stride = gridDim.x * blockDim.x;
    for (int i = blockIdx.x * blockDim.x + threadIdx.x; i < n4; i += stride) {
        float4 v = ((const float4*)in)[i];
        bf16x4 o;
        o[0] = (bf16)v.x; o[1] = (bf16)v.y; o[2] = (bf16)v.z; o[3] = (bf16)v.w;
        ((bf16x4*)out)[i] = o;
    }
}

// ---------------- 256x256 8-phase GEMM: C[m,n] = sum_k A[m,k]*B[n,k] ----------------
// A: M x K row-major bf16, B: N x K row-major bf16, C: M x N row-major OutT.
// 512 thr = 8 waves (2Mx4N), per-wave 128x64 out, BK=64, 2 K-tiles / 8 phases per iter.
// LDS 128 KB (2 dbuf x 2 half x (A,B) x 16 KB), 1 block/CU.
// Swizzle: LDS[row][slot] = global[row][slot ^ (row&7)] (16B slots), via pre-swizzled
// global source (global_load_lds dest must be linear), XOR applied again on ds_read.
template <typename OutT>
__global__ __launch_bounds__(512, 2) void gemm256(const bf16* __restrict__ A,
                                                  const bf16* __restrict__ Bm,
                                                  OutT* __restrict__ C, int M, int N, int K) {
    __shared__ __align__(16) bf16 As[2][2][128 * 64];
    __shared__ __align__(16) bf16 Bs[2][2][128 * 64];
    (void)M;
    int tiles_n = N >> 8;
    int nwg = gridDim.x;
    int bid = blockIdx.x;
    int wg = (bid & 7) * (nwg >> 3) + (bid >> 3);  // XCD swizzle (nwg % 8 == 0)
    int bm = wg / tiles_n, bn = wg % tiles_n;
    int tid = threadIdx.x;
    int lane = tid & 63, w = tid >> 6;
    int l15 = lane & 15, lg = lane >> 4, l7 = l15 & 7;
    int wm = w >> 2, wn = w & 3;
    const bf16* Ab = A + (size_t)bm * 256 * K;
    const bf16* Bb = Bm + (size_t)bn * 256 * K;

    // stage one 128x64 half-tile (16 KB): 2 x global_load_lds(16B) per thread
    auto stageA = [&](int buf, int h, int kt) {
#pragma unroll
        for (int l = 0; l < 2; ++l) {
            int o = l * 8192 + tid * 16;
            int row = o >> 7, slot = (o >> 4) & 7;
            __builtin_amdgcn_global_load_lds(
                (GV*)(Ab + (size_t)(h * 128 + row) * K + kt * 64 + ((slot ^ (row & 7)) << 3)),
                (SV*)((char*)As[buf][h] + o), 16, 0, 0);
        }
    };
    auto stageB = [&](int buf, int h, int kt) {
#pragma unroll
        for (int l = 0; l < 2; ++l) {
            int o = l * 8192 + tid * 16;
            int row = o >> 7, slot = (o >> 4) & 7;
            __builtin_amdgcn_global_load_lds(
                (GV*)(Bb + (size_t)(h * 128 + row) * K + kt * 64 + ((slot ^ (row & 7)) << 3)),
                (SV*)((char*)Bs[buf][h] + o), 16, 0, 0);
        }
    };
    // fragment reads (row&7 == l7 for both since rows are l15 mod 16)
    auto rdA = [&](int buf, int fr, int kk) -> bf16x8 {
        int off = (fr * 16 + l15) * 128 + ((((kk << 2) | lg) ^ l7) << 4);
        return *(const bf16x8*)((const char*)As[buf][wm] + off);
    };
    auto rdB = [&](int buf, int fc, int kk) -> bf16x8 {
        int off = ((wn & 1) * 64 + fc * 16 + l15) * 128 + ((((kk << 2) | lg) ^ l7) << 4);
        return *(const bf16x8*)((const char*)Bs[buf][wn >> 1] + off);
    };

    floatx4 acc[8][4] = {};
    bf16x8 aF[4][2], bF[4][2];
    int nk = K >> 6, niter = nk >> 1;

    // prologue: K0 all 4 halves -> dbuf0; K1 B halves -> dbuf1
    stageA(0, 0, 0); stageA(0, 1, 0); stageB(0, 0, 0); stageB(0, 1, 0);
    stageB(1, 0, 1); stageB(1, 1, 1);
    asm volatile("s_waitcnt vmcnt(4)" ::: "memory");
    __builtin_amdgcn_sched_barrier(0);
    BAR();

    auto quad = [&](int ra, int ca) {
        __builtin_amdgcn_s_setprio(1);
#pragma unroll
        for (int fr = 0; fr < 4; ++fr)
#pragma unroll
            for (int fc = 0; fc < 2; ++fc)
#pragma unroll
                for (int kk = 0; kk < 2; ++kk)
                    acc[ra * 4 + fr][ca * 2 + fc] = __builtin_amdgcn_mfma_f32_16x16x32_bf16(
                        aF[fr][kk], bF[ca * 2 + fc][kk], acc[ra * 4 + fr][ca * 2 + fc], 0, 0, 0);
        __builtin_amdgcn_s_setprio(0);
    };

    for (int i = 0; i < niter; ++i) {
        bool nl = (i + 1 < niter);
        int kt1 = 2 * i + 1, kt2 = 2 * i + 2, kt3 = 2 * i + 3;
        // ---- P0: dbuf0 A rows0-3 + B cols0-1; stage K(2i+1) A-h0 -> dbuf1
#pragma unroll
        for (int fr = 0; fr < 4; ++fr)
#pragma unroll
            for (int kk = 0; kk < 2; ++kk) aF[fr][kk] = rdA(0, fr, kk);
#pragma unroll
        for (int fc = 0; fc < 2; ++fc)
#pragma unroll
            for (int kk = 0; kk < 2; ++kk) bF[fc][kk] = rdB(0, fc, kk);
        stageA(1, 0, kt1);
        BAR();
        quad(0, 0);
        BAR();
        // ---- P1: dbuf0 B cols2-3; stage K(2i+1) A-h1 -> dbuf1
#pragma unroll
        for (int fc = 2; fc < 4; ++fc)
#pragma unroll
            for (int kk = 0; kk < 2; ++kk) bF[fc][kk] = rdB(0, fc, kk);
        stageA(1, 1, kt1);
        BAR();
        quad(0, 1);
        BAR();
        // ---- P2: dbuf0 A rows4-7; stage K(2i+2) B-h0 -> dbuf0
#pragma unroll
        for (int fr = 0; fr < 4; ++fr)
#pragma unroll
            for (int kk = 0; kk < 2; ++kk) aF[fr][kk] = rdA(0, 4 + fr, kk);
        if (nl) stageB(0, 0, kt2);
        BAR();
        quad(1, 0);
        BAR();
        // ---- P3: stage K(2i+2) B-h1 -> dbuf0; vmcnt before closing barrier
        if (nl) stageB(0, 1, kt2);
        BAR();
        quad(1, 1);
        if (nl) asm volatile("s_waitcnt vmcnt(4)" ::: "memory");
        else    asm volatile("s_waitcnt vmcnt(0)" ::: "memory");
        __builtin_amdgcn_sched_barrier(0);
        BAR();
        // ---- P4: dbuf1 A rows0-3 + B cols0-1; stage K(2i+2) A-h0 -> dbuf0
#pragma unroll
        for (int fr = 0; fr < 4; ++fr)
#pragma unroll
            for (int kk = 0; kk < 2; ++kk) aF[fr][kk] = rdA(1, fr, kk);
#pragma unroll
        for (int fc = 0; fc < 2; ++fc)
#pragma unroll
            for (int kk = 0; kk < 2; ++kk) bF[fc][kk] = rdB(1, fc, kk);
        if (nl) stageA(0, 0, kt2);
        BAR();
        quad(0, 0);
        BAR();
        // ---- P5: dbuf1 B cols2-3; stage K(2i+2) A-h1 -> dbuf0
#pragma unroll
        for (int fc = 2; fc < 4; ++fc)
#pragma unroll
            for (int kk = 0; kk < 2; ++kk) bF[fc][kk] = rdB(1, fc, kk);
        if (nl) stageA(0, 1, kt2);
        BAR();
        quad(0, 1);
        BAR();
        // ---- P6: dbuf1 A rows4-7; stage K(2i+3) B-h0 -> dbuf1
#pragma unroll
        for (int fr = 0; fr < 4; ++fr)
#pragma unroll
            for (int kk = 0; kk < 2; ++kk) aF[fr][kk] = rdA(1, 4 + fr, kk);
        if (nl) stageB(1, 0, kt3);
        BAR();
        quad(1, 0);
        BAR();
        // ---- P7: stage K(2i+3) B-h1 -> dbuf1; vmcnt before closing barrier
        if (nl) stageB(1, 1, kt3);
        BAR();
        quad(1, 1);
        asm volatile("s_waitcnt vmcnt(4)" ::: "memory");
        __builtin_amdgcn_sched_barrier(0);
        BAR();
    }

    // ---- epilogue: C write
    int brow = bm * 256 + wm * 128, bcol = bn * 256 + wn * 64;
#pragma unroll
    for (int fr = 0; fr < 8; ++fr)
#pragma unroll
        for (int fc = 0; fc < 4; ++fc) {
            int col = bcol + fc * 16 + l15;
#pragma unroll
            for (int r = 0; r < 4; ++r) {
                int row = brow + fr * 16 + lg * 4 + r;
                C[(size_t)row * N + col] = (OutT)acc[fr][fc][r];
            }
        }
}

// ---------------- RoPE + reshape (Q pre-scaled by SCALING) ----------------
__global__ __launch_bounds__(256) void rope_qk(const bf16* __restrict__ qkv,
                                               const float* __restrict__ cosp,
                                               const float* __restrict__ sinp,
                                               bf16* __restrict__ Q, bf16* __restrict__ K) {
    int bs = blockIdx.x;
    int b = bs >> 11, s = bs & (S_LEN - 1);
    const bf16* row = qkv + (size_t)bs * QKVW;
    const float* cr = cosp + (size_t)bs * HD;
    const float* sr = sinp + (size_t)bs * HD;
    int t = threadIdx.x;
    int h = t >> 3, d0 = (t & 7) * 8;
    {
        bf16x8 x1 = *(const bf16x8*)(row + h * HD + d0);
        bf16x8 x2 = *(const bf16x8*)(row + h * HD + 64 + d0);
        bf16x8 o1, o2;
#pragma unroll
        for (int j = 0; j < 8; ++j) {
            float a = (float)x1[j], bv = (float)x2[j];
            o1[j] = (bf16)((a * cr[d0 + j] - bv * sr[d0 + j]) * SCALING);
            o2[j] = (bf16)((bv * cr[64 + d0 + j] + a * sr[64 + d0 + j]) * SCALING);
        }
        size_t qb = (((size_t)b * NH + h) * S_LEN + s) * HD;
        *(bf16x8*)(Q + qb + d0) = o1;
        *(bf16x8*)(Q + qb + 64 + d0) = o2;
    }
    if (t < 64) {
        int kh = t >> 3;
        bf16x8 x1 = *(const bf16x8*)(row + QSZ + kh * HD + d0);
        bf16x8 x2 = *(const bf16x8*)(row + QSZ + kh * HD + 64 + d0);
        bf16x8 o1, o2;
#pragma unroll
        for (int j = 0; j < 8; ++j) {
            float a = (float)x1[j], bv = (float)x2[j];
            o1[j] = (bf16)(a * cr[d0 + j] - bv * sr[d0 + j]);
            o2[j] = (bf16)(bv * cr[64 + d0 + j] + a * sr[64 + d0 + j]);
        }
        size_t kb = (((size_t)b * NKV + kh) * S_LEN + s) * HD;
        *(bf16x8*)(K + kb + d0) = o1;
        *(bf16x8*)(K + kb + 64 + d0) = o2;
    }
}

// ---------------- V transpose: qkv v-slice -> Vt[B,NKV,HD,S] ----------------
__global__ __launch_bounds__(256) void v_transpose(const bf16* __restrict__ qkv,
                                                   bf16* __restrict__ Vt) {
    int bid = blockIdx.x;
    int dt = bid & 1, st = (bid >> 1) & 31, bk = bid >> 6;
    int b = bk >> 3, kv = bk & 7;
    __shared__ __align__(16) bf16 tile[64][72];
    int t = threadIdx.x;
#pragma unroll
    for (int it = 0; it < 2; ++it) {
        int i = it * 32 + (t >> 3);
        int j8 = (t & 7) * 8;
        bf16x8 v = *(const bf16x8*)(qkv + ((size_t)(b * S_LEN + st * 64 + i)) * QKVW +
                                    QSZ + KVSZ + kv * HD + dt * 64 + j8);
        *(bf16x8*)&tile[i][j8] = v;
    }
    __syncthreads();
    int dl = t >> 2, s8 = (t & 3) * 16;
    bf16x8 o0, o1;
#pragma unroll
    for (int u = 0; u < 8; ++u) { o0[u] = tile[s8 + u][dl]; o1[u] = tile[s8 + 8 + u][dl]; }
    size_t ob = (((size_t)b * NKV + kv) * HD + dt * 64 + dl) * S_LEN + st * 64 + s8;
    *(bf16x8*)(Vt + ob) = o0;
    *(bf16x8*)(Vt + ob + 8) = o1;
}

// ---------------- causal GQA flash attention (swapped-QK, dbuf, swizzled LDS) ----------
__global__ __launch_bounds__(256, 2) void attn_fwd(const bf16* __restrict__ Q,
                                                   const bf16* __restrict__ K,
                                                   const bf16* __restrict__ Vt,
                                                   bf16* __restrict__ O) {
    __shared__ __align__(16) bf16 Ks[2][64 * 128];
    __shared__ __align__(16) bf16 Vs[2][128 * 64];
    __shared__ __align__(16) bf16 Ps[4][32 * 64];

    int bid = blockIdx.x;
    int qt = bid & 15, bh = bid >> 4, h = bh & 31, b = bh >> 5;
    int kvh = h >> 2;
    int tid = threadIdx.x, lane = tid & 63, w = tid >> 6;
    int l15 = lane & 15, lg = lane >> 4, l7 = l15 & 7, lg4 = lg * 4;
    int q0 = qt * 128;
    int qbw = q0 + w * 32;

    const bf16* Qb = Q + ((size_t)(b * NH + h) * S_LEN) * HD;
    const bf16* Kb = K + ((size_t)(b * NKV + kvh) * S_LEN) * HD;
    const bf16* Vb = Vt + ((size_t)(b * NKV + kvh) * HD) * S_LEN;

    bf16x8 qf[2][4];
#pragma unroll
    for (int i = 0; i < 2; ++i)
#pragma unroll
        for (int ks = 0; ks < 4; ++ks)
            qf[i][ks] = *(const bf16x8*)(Qb + (size_t)(qbw + i * 16 + l15) * HD + ks * 32 + lg * 8);

    floatx4 accO[2][8] = {};
    float m_run[2] = {-1e30f, -1e30f}, l_run[2] = {0.f, 0.f};

    char* Pc = (char*)Ps[w];
    int nt = 2 * qt + 2;

    auto stage = [&](int buf, int t) {
        int kv0 = t * 64;
#pragma unroll
        for (int it = 0; it < 4; ++it) {
            int o = it * 4096 + tid * 16;
            int r = o >> 8, pb = (o >> 4) & 15;
            int lb = pb ^ (r & 7);
            __builtin_amdgcn_global_load_lds((GV*)(Kb + (size_t)(kv0 + r) * HD + lb * 8),
                                             (SV*)((char*)Ks[buf] + o), 16, 0, 0);
        }
#pragma unroll
        for (int it = 0; it < 4; ++it) {
            int o = it * 4096 + tid * 16;
            int d = o >> 7, pb = (o >> 4) & 7;
            int lb = pb ^ (d & 7);
            __builtin_amdgcn_global_load_lds((GV*)(Vb + (size_t)d * S_LEN + kv0 + lb * 8),
                                             (SV*)((char*)Vs[buf] + o), 16, 0, 0);
        }
    };

    stage(0, 0);
    __syncthreads();

    for (int t = 0; t < nt; ++t) {
        int cur = t & 1;
        if (t + 1 < nt) stage(cur ^ 1, t + 1);
        int kv0 = t * 64;
        const char* Kc = (const char*)Ks[cur];
        const char* Vc = (const char*)Vs[cur];

        floatx4 s[2][4] = {};
#pragma unroll
        for (int nm = 0; nm < 4; ++nm)
#pragma unroll
            for (int ks = 0; ks < 4; ++ks) {
                bf16x8 kf = *(const bf16x8*)(Kc + (nm * 16 + l15) * 256 +
                                             ((((ks << 2) | lg) ^ l7) << 4));
                s[0][nm] = __builtin_amdgcn_mfma_f32_16x16x32_bf16(kf, qf[0][ks], s[0][nm], 0, 0, 0);
                s[1][nm] = __builtin_amdgcn_mfma_f32_16x16x32_bf16(kf, qf[1][ks], s[1][nm], 0, 0, 0);
            }

#pragma unroll
        for (int i = 0; i < 2; ++i) {
            if (kv0 + 63 > qbw + i * 16) {
                int qg = qbw + i * 16 + l15;
#pragma unroll
                for (int nm = 0; nm < 4; ++nm)
#pragma unroll
                    for (int r = 0; r < 4; ++r)
                        if (kv0 + nm * 16 + lg4 + r > qg) s[i][nm][r] = -1e30f;
            }
            float mx = -1e30f;
#pragma unroll
            for (int nm = 0; nm < 4; ++nm)
#pragma unroll
                for (int r = 0; r < 4; ++r) mx = fmaxf(mx, s[i][nm][r]);
            mx = fmaxf(mx, __shfl_xor(mx, 16));
            mx = fmaxf(mx, __shfl_xor(mx, 32));
            float mn = fmaxf(m_run[i], mx);
            float corr = __expf(m_run[i] - mn);
            m_run[i] = mn;
            float sum = 0.f;
#pragma unroll
            for (int nm = 0; nm < 4; ++nm) {
                bf16x4 pk;
#pragma unroll
                for (int r = 0; r < 4; ++r) {
                    float p = __expf(s[i][nm][r] - mn);
                    sum += p;
                    pk[r] = (bf16)p;
                }
                *(bf16x4*)(Pc + (i * 16 + l15) * 128 +
                           ((((nm << 1) | (lg >> 1)) ^ l7) << 4) + ((lg & 1) << 3)) = pk;
            }
            sum += __shfl_xor(sum, 16);
            sum += __shfl_xor(sum, 32);
            l_run[i] = l_run[i] * corr + sum;
#pragma unroll
            for (int r = 0; r < 4; ++r) {
                float cr = __shfl(corr, lg4 + r);
#pragma unroll
                for (int g = 0; g < 8; ++g) accO[i][g][r] *= cr;
            }
        }
        asm volatile("s_waitcnt lgkmcnt(0)" ::: "memory");

        bf16x8 pf[2][2];
#pragma unroll
        for (int i = 0; i < 2; ++i)
#pragma unroll
            for (int ks = 0; ks < 2; ++ks)
                pf[i][ks] = *(const bf16x8*)(Pc + (i * 16 + l15) * 128 +
                                             ((((ks << 2) | lg) ^ l7) << 4));
#pragma unroll
        for (int g = 0; g < 8; ++g)
#pragma unroll
            for (int ks = 0; ks < 2; ++ks) {
                bf16x8 vf = *(const bf16x8*)(Vc + (g * 16 + l15) * 128 +
                                             ((((ks << 2) | lg) ^ l7) << 4));
                accO[0][g] = __builtin_amdgcn_mfma_f32_16x16x32_bf16(pf[0][ks], vf, accO[0][g], 0, 0, 0);
                accO[1][g] = __builtin_amdgcn_mfma_f32_16x16x32_bf16(pf[1][ks], vf, accO[1][g], 0, 0, 0);
            }
        __syncthreads();
    }

#pragma unroll
    for (int i = 0; i < 2; ++i) {
        float inv = 1.f / l_run[i];
#pragma unroll
        for (int r = 0; r < 4; ++r) {
            float vinv = __shfl(inv, lg4 + r);
            int qg = qbw + i * 16 + lg4 + r;
            size_t ob = ((size_t)(b * S_LEN + qg) * NH + h) * HD;
#pragma unroll
            for (int g = 0; g < 8; ++g)
                O[ob + g * 16 + l15] = (bf16)(accO[i][g][r] * vinv);
        }
    }
}

extern "C" void kernel_launch(void* const* d_in, const int* in_sizes, int n_in,
                              void* d_out, int out_size, void* d_ws, size_t ws_size,
                              hipStream_t stream) {
    const float* hs   = (const float*)d_in[0];
    const float* cosp = (const float*)d_in[1];
    const float* sinp = (const float*)d_in[2];
    const float* wqkv = (const float*)d_in[3];
    const float* wo   = (const float*)d_in[4];
    float* out = (float*)d_out;

    char* ws = (char*)d_ws;
    size_t off = 0;
    auto alloc = [&](size_t bytes) {
        char* p = ws + off;
        off += (bytes + 255) & ~(size_t)255;
        return p;
    };
    const size_t n_hs = (size_t)B_DIM * S_LEN * HID;
    const size_t n_wqkv = (size_t)QKVW * HID;
    const size_t n_wo = (size_t)HID * QSZ;
    const size_t n_qkv = (size_t)B_DIM * S_LEN * QKVW;

    bf16* hs_b   = (bf16*)alloc(n_hs * 2);
    bf16* wqkv_b = (bf16*)alloc(n_wqkv * 2);
    bf16* wo_b   = (bf16*)alloc(n_wo * 2);
    bf16* qkv_b  = (bf16*)alloc(n_qkv * 2);
    bf16* Qb  = (bf16*)alloc((size_t)B_DIM * NH * S_LEN * HD * 2);
    bf16* Kb  = (bf16*)alloc((size_t)B_DIM * NKV * S_LEN * HD * 2);
    bf16* Vtb = (bf16*)alloc((size_t)B_DIM * NKV * HD * S_LEN * 2);
    bf16* attn_b = hs_b;  // hs_b dead after gemm1

    cvt_f32_bf16<<<1024, 256, 0, stream>>>(hs, hs_b, (int)n_hs);
    cvt_f32_bf16<<<1024, 256, 0, stream>>>(wqkv, wqkv_b, (int)n_wqkv);
    cvt_f32_bf16<<<1024, 256, 0, stream>>>(wo, wo_b, (int)n_wo);

    gemm256<bf16><<<(4096 / 256) * (6144 / 256), 512, 0, stream>>>(
        hs_b, wqkv_b, qkv_b, B_DIM * S_LEN, QKVW, HID);

    rope_qk<<<B_DIM * S_LEN, 256, 0, stream>>>(qkv_b, cosp, sinp, Qb, Kb);
    v_transpose<<<B_DIM * NKV * (S_LEN / 64) * (HD / 64), 256, 0, stream>>>(qkv_b, Vtb);

    attn_fwd<<<B_DIM * NH * (S_LEN / 128), 256, 0, stream>>>(Qb, Kb, Vtb, attn_b);

    gemm256<float><<<(4096 / 256) * (4096 / 256), 512, 0, stream>>>(
        attn_b, wo_b, out, B_DIM * S_LEN, HID, HID);
}

// Round 4
// 590.354 us; speedup vs baseline: 1.6210x; 1.0501x over previous
//
#include <hip/hip_runtime.h>
#include <hip/hip_bf16.h>
#include <cstdint>

#define B_DIM 2
#define S_LEN 2048
#define HID 4096
#define NH 32
#define NKV 8
#define HD 128
#define QSZ (NH * HD)          // 4096
#define KVSZ (NKV * HD)        // 1024
#define QKVW (QSZ + 2 * KVSZ)  // 6144
#define SCALING 0.08838834764831845f

typedef __bf16 bf16;
typedef __bf16 bf16x4 __attribute__((ext_vector_type(4)));
typedef __bf16 bf16x8 __attribute__((ext_vector_type(8)));
typedef float floatx4 __attribute__((ext_vector_type(4)));

typedef __attribute__((address_space(1))) void GV;
typedef __attribute__((address_space(3))) void SV;

#define BAR() __builtin_amdgcn_s_barrier()

// ---------------- f32 -> bf16 convert ----------------
__global__ __launch_bounds__(256) void cvt_f32_bf16(const float* __restrict__ in,
                                                    bf16* __restrict__ out, int n) {
    int n4 = n >> 2;
    int stride = gridDim.x * blockDim.x;
    for (int i = blockIdx.x * blockDim.x + threadIdx.x; i < n4; i += stride) {
        float4 v = ((const float4*)in)[i];
        bf16x4 o;
        o[0] = (bf16)v.x; o[1] = (bf16)v.y; o[2] = (bf16)v.z; o[3] = (bf16)v.w;
        ((bf16x4*)out)[i] = o;
    }
}

// ---------------- 256x256 8-phase GEMM: C[m,n] = sum_k A[m,k]*B[n,k] ----------------
// tiles_m, tiles_n both divisible by 4 (supertile mapping); grid % 8 == 0 (XCD swizzle).
template <typename OutT>
__global__ __launch_bounds__(512, 2) void gemm256(const bf16* __restrict__ A,
                                                  const bf16* __restrict__ Bm,
                                                  OutT* __restrict__ C, int M, int N, int K) {
    __shared__ __align__(16) bf16 As[2][2][128 * 64];
    __shared__ __align__(16) bf16 Bs[2][2][128 * 64];
    (void)M;
    int tiles_n = N >> 8;
    int nwg = gridDim.x;
    int bid = blockIdx.x;
    int wg = (bid & 7) * (nwg >> 3) + (bid >> 3);  // XCD chunking
    // 4x4 supertile order within the linear wg sequence -> L2 locality
    int st = wg >> 4, within = wg & 15;
    int stn = tiles_n >> 2;
    int bm = (st / stn) * 4 + (within >> 2);
    int bn = (st % stn) * 4 + (within & 3);
    int tid = threadIdx.x;
    int lane = tid & 63, w = tid >> 6;
    int l15 = lane & 15, lg = lane >> 4, l7 = l15 & 7;
    int wm = w >> 2, wn = w & 3;
    const bf16* Ab = A + (size_t)bm * 256 * K;
    const bf16* Bb = Bm + (size_t)bn * 256 * K;

    // precomputed per-thread staging offsets (elements)
    int o_lo = tid * 16, o_hi = o_lo + 8192;
    int r_lo = o_lo >> 7, r_hi = o_hi >> 7;
    int eo0 = r_lo * K + ((((o_lo >> 4) & 7) ^ (r_lo & 7)) << 3);
    int eo1 = r_hi * K + ((((o_hi >> 4) & 7) ^ (r_hi & 7)) << 3);
    const bf16* AbH[2] = {Ab, Ab + (size_t)128 * K};
    const bf16* BbH[2] = {Bb, Bb + (size_t)128 * K};

    auto stageA = [&](int buf, int h, int kt) {
        const bf16* base = AbH[h] + kt * 64;
        __builtin_amdgcn_global_load_lds((GV*)(base + eo0), (SV*)((char*)As[buf][h] + o_lo), 16, 0, 0);
        __builtin_amdgcn_global_load_lds((GV*)(base + eo1), (SV*)((char*)As[buf][h] + o_hi), 16, 0, 0);
    };
    auto stageB = [&](int buf, int h, int kt) {
        const bf16* base = BbH[h] + kt * 64;
        __builtin_amdgcn_global_load_lds((GV*)(base + eo0), (SV*)((char*)Bs[buf][h] + o_lo), 16, 0, 0);
        __builtin_amdgcn_global_load_lds((GV*)(base + eo1), (SV*)((char*)Bs[buf][h] + o_hi), 16, 0, 0);
    };
    auto rdA = [&](int buf, int fr, int kk) -> bf16x8 {
        int off = (fr * 16 + l15) * 128 + ((((kk << 2) | lg) ^ l7) << 4);
        return *(const bf16x8*)((const char*)As[buf][wm] + off);
    };
    auto rdB = [&](int buf, int fc, int kk) -> bf16x8 {
        int off = ((wn & 1) * 64 + fc * 16 + l15) * 128 + ((((kk << 2) | lg) ^ l7) << 4);
        return *(const bf16x8*)((const char*)Bs[buf][wn >> 1] + off);
    };

    floatx4 acc[8][4] = {};
    bf16x8 aF[4][2], bF[4][2];
    int nk = K >> 6, niter = nk >> 1;

    stageA(0, 0, 0); stageA(0, 1, 0); stageB(0, 0, 0); stageB(0, 1, 0);
    stageB(1, 0, 1); stageB(1, 1, 1);
    asm volatile("s_waitcnt vmcnt(4)" ::: "memory");
    __builtin_amdgcn_sched_barrier(0);
    BAR();

    auto quad = [&](int ra, int ca) {
        __builtin_amdgcn_s_setprio(1);
#pragma unroll
        for (int fr = 0; fr < 4; ++fr)
#pragma unroll
            for (int fc = 0; fc < 2; ++fc)
#pragma unroll
                for (int kk = 0; kk < 2; ++kk)
                    acc[ra * 4 + fr][ca * 2 + fc] = __builtin_amdgcn_mfma_f32_16x16x32_bf16(
                        aF[fr][kk], bF[ca * 2 + fc][kk], acc[ra * 4 + fr][ca * 2 + fc], 0, 0, 0);
        __builtin_amdgcn_s_setprio(0);
    };

    for (int i = 0; i < niter; ++i) {
        bool nl = (i + 1 < niter);
        int kt1 = 2 * i + 1, kt2 = 2 * i + 2, kt3 = 2 * i + 3;
        // P0
#pragma unroll
        for (int fr = 0; fr < 4; ++fr)
#pragma unroll
            for (int kk = 0; kk < 2; ++kk) aF[fr][kk] = rdA(0, fr, kk);
#pragma unroll
        for (int fc = 0; fc < 2; ++fc)
#pragma unroll
            for (int kk = 0; kk < 2; ++kk) bF[fc][kk] = rdB(0, fc, kk);
        stageA(1, 0, kt1);
        BAR(); quad(0, 0); BAR();
        // P1
#pragma unroll
        for (int fc = 2; fc < 4; ++fc)
#pragma unroll
            for (int kk = 0; kk < 2; ++kk) bF[fc][kk] = rdB(0, fc, kk);
        stageA(1, 1, kt1);
        BAR(); quad(0, 1); BAR();
        // P2
#pragma unroll
        for (int fr = 0; fr < 4; ++fr)
#pragma unroll
            for (int kk = 0; kk < 2; ++kk) aF[fr][kk] = rdA(0, 4 + fr, kk);
        if (nl) stageB(0, 0, kt2);
        BAR(); quad(1, 0); BAR();
        // P3
        if (nl) stageB(0, 1, kt2);
        BAR(); quad(1, 1);
        if (nl) asm volatile("s_waitcnt vmcnt(4)" ::: "memory");
        else    asm volatile("s_waitcnt vmcnt(0)" ::: "memory");
        __builtin_amdgcn_sched_barrier(0);
        BAR();
        // P4
#pragma unroll
        for (int fr = 0; fr < 4; ++fr)
#pragma unroll
            for (int kk = 0; kk < 2; ++kk) aF[fr][kk] = rdA(1, fr, kk);
#pragma unroll
        for (int fc = 0; fc < 2; ++fc)
#pragma unroll
            for (int kk = 0; kk < 2; ++kk) bF[fc][kk] = rdB(1, fc, kk);
        if (nl) stageA(0, 0, kt2);
        BAR(); quad(0, 0); BAR();
        // P5
#pragma unroll
        for (int fc = 2; fc < 4; ++fc)
#pragma unroll
            for (int kk = 0; kk < 2; ++kk) bF[fc][kk] = rdB(1, fc, kk);
        if (nl) stageA(0, 1, kt2);
        BAR(); quad(0, 1); BAR();
        // P6
#pragma unroll
        for (int fr = 0; fr < 4; ++fr)
#pragma unroll
            for (int kk = 0; kk < 2; ++kk) aF[fr][kk] = rdA(1, 4 + fr, kk);
        if (nl) stageB(1, 0, kt3);
        BAR(); quad(1, 0); BAR();
        // P7
        if (nl) stageB(1, 1, kt3);
        BAR(); quad(1, 1);
        asm volatile("s_waitcnt vmcnt(4)" ::: "memory");
        __builtin_amdgcn_sched_barrier(0);
        BAR();
    }

    int brow = bm * 256 + wm * 128, bcol = bn * 256 + wn * 64;
#pragma unroll
    for (int fr = 0; fr < 8; ++fr)
#pragma unroll
        for (int fc = 0; fc < 4; ++fc) {
            int col = bcol + fc * 16 + l15;
#pragma unroll
            for (int r = 0; r < 4; ++r) {
                int row = brow + fr * 16 + lg * 4 + r;
                C[(size_t)row * N + col] = (OutT)acc[fr][fc][r];
            }
        }
}

// ---------------- RoPE + reshape (Q pre-scaled by SCALING) ----------------
__global__ __launch_bounds__(256) void rope_qk(const bf16* __restrict__ qkv,
                                               const float* __restrict__ cosp,
                                               const float* __restrict__ sinp,
                                               bf16* __restrict__ Q, bf16* __restrict__ K) {
    int bs = blockIdx.x;
    int b = bs >> 11, s = bs & (S_LEN - 1);
    const bf16* row = qkv + (size_t)bs * QKVW;
    const float* cr = cosp + (size_t)bs * HD;
    const float* sr = sinp + (size_t)bs * HD;
    int t = threadIdx.x;
    int h = t >> 3, d0 = (t & 7) * 8;
    {
        bf16x8 x1 = *(const bf16x8*)(row + h * HD + d0);
        bf16x8 x2 = *(const bf16x8*)(row + h * HD + 64 + d0);
        bf16x8 o1, o2;
#pragma unroll
        for (int j = 0; j < 8; ++j) {
            float a = (float)x1[j], bv = (float)x2[j];
            o1[j] = (bf16)((a * cr[d0 + j] - bv * sr[d0 + j]) * SCALING);
            o2[j] = (bf16)((bv * cr[64 + d0 + j] + a * sr[64 + d0 + j]) * SCALING);
        }
        size_t qb = (((size_t)b * NH + h) * S_LEN + s) * HD;
        *(bf16x8*)(Q + qb + d0) = o1;
        *(bf16x8*)(Q + qb + 64 + d0) = o2;
    }
    if (t < 64) {
        int kh = t >> 3;
        bf16x8 x1 = *(const bf16x8*)(row + QSZ + kh * HD + d0);
        bf16x8 x2 = *(const bf16x8*)(row + QSZ + kh * HD + 64 + d0);
        bf16x8 o1, o2;
#pragma unroll
        for (int j = 0; j < 8; ++j) {
            float a = (float)x1[j], bv = (float)x2[j];
            o1[j] = (bf16)(a * cr[d0 + j] - bv * sr[d0 + j]);
            o2[j] = (bf16)(bv * cr[64 + d0 + j] + a * sr[64 + d0 + j]);
        }
        size_t kb = (((size_t)b * NKV + kh) * S_LEN + s) * HD;
        *(bf16x8*)(K + kb + d0) = o1;
        *(bf16x8*)(K + kb + 64 + d0) = o2;
    }
}

// ---------------- V transpose: qkv v-slice -> Vt[B,NKV,HD,S] ----------------
__global__ __launch_bounds__(256) void v_transpose(const bf16* __restrict__ qkv,
                                                   bf16* __restrict__ Vt) {
    int bid = blockIdx.x;
    int dt = bid & 1, st = (bid >> 1) & 31, bk = bid >> 6;
    int b = bk >> 3, kv = bk & 7;
    __shared__ __align__(16) bf16 tile[64][72];
    int t = threadIdx.x;
#pragma unroll
    for (int it = 0; it < 2; ++it) {
        int i = it * 32 + (t >> 3);
        int j8 = (t & 7) * 8;
        bf16x8 v = *(const bf16x8*)(qkv + ((size_t)(b * S_LEN + st * 64 + i)) * QKVW +
                                    QSZ + KVSZ + kv * HD + dt * 64 + j8);
        *(bf16x8*)&tile[i][j8] = v;
    }
    __syncthreads();
    int dl = t >> 2, s8 = (t & 3) * 16;
    bf16x8 o0, o1;
#pragma unroll
    for (int u = 0; u < 8; ++u) { o0[u] = tile[s8 + u][dl]; o1[u] = tile[s8 + 8 + u][dl]; }
    size_t ob = (((size_t)b * NKV + kv) * HD + dt * 64 + dl) * S_LEN + st * 64 + s8;
    *(bf16x8*)(Vt + ob) = o0;
    *(bf16x8*)(Vt + ob + 8) = o1;
}

// ---------------- causal GQA flash attention ----------------
// 64KB LDS -> 2 blocks/CU. K dbuf, V single-buf, counted-vmcnt pipeline, defer-max.
__global__ __launch_bounds__(256, 2) void attn_fwd(const bf16* __restrict__ Q,
                                                   const bf16* __restrict__ K,
                                                   const bf16* __restrict__ Vt,
                                                   bf16* __restrict__ O) {
    __shared__ __align__(16) bf16 Ks[2][64 * 128];   // 2 x 16 KB
    __shared__ __align__(16) bf16 Vs[128 * 64];      // 16 KB
    __shared__ __align__(16) bf16 Ps[4][32 * 64];    // 16 KB

    int nwg = gridDim.x;
    int bid0 = blockIdx.x;
    int bid = (bid0 & 7) * (nwg >> 3) + (bid0 >> 3);  // XCD chunking (nwg%8==0)
    int qt = bid & 15, bh = bid >> 4, h = bh & 31, b = bh >> 5;
    int kvh = h >> 2;
    int tid = threadIdx.x, lane = tid & 63, w = tid >> 6;
    int l15 = lane & 15, lg = lane >> 4, l7 = l15 & 7, lg4 = lg * 4;
    int q0 = qt * 128;
    int qbw = q0 + w * 32;

    const bf16* Qb = Q + ((size_t)(b * NH + h) * S_LEN) * HD;
    const bf16* Kb = K + ((size_t)(b * NKV + kvh) * S_LEN) * HD;
    const bf16* Vb = Vt + ((size_t)(b * NKV + kvh) * HD) * S_LEN;

    bf16x8 qf[2][4];
#pragma unroll
    for (int i = 0; i < 2; ++i)
#pragma unroll
        for (int ks = 0; ks < 4; ++ks)
            qf[i][ks] = *(const bf16x8*)(Qb + (size_t)(qbw + i * 16 + l15) * HD + ks * 32 + lg * 8);

    floatx4 accO[2][8] = {};
    float m_run[2] = {-1e30f, -1e30f}, l_run[2] = {0.f, 0.f};

    char* Pc = (char*)Ps[w];
    int nt = 2 * qt + 2;

    auto stageK = [&](int buf, int t) {
        int kv0 = t * 64;
#pragma unroll
        for (int it = 0; it < 4; ++it) {
            int o = it * 4096 + tid * 16;
            int r = o >> 8, pb = (o >> 4) & 15;
            int lb = pb ^ (r & 7);
            __builtin_amdgcn_global_load_lds((GV*)(Kb + (size_t)(kv0 + r) * HD + lb * 8),
                                             (SV*)((char*)Ks[buf] + o), 16, 0, 0);
        }
    };
    auto stageV = [&](int t) {
        int kv0 = t * 64;
#pragma unroll
        for (int it = 0; it < 4; ++it) {
            int o = it * 4096 + tid * 16;
            int d = o >> 7, pb = (o >> 4) & 7;
            int lb = pb ^ (d & 7);
            __builtin_amdgcn_global_load_lds((GV*)(Vb + (size_t)d * S_LEN + kv0 + lb * 8),
                                             (SV*)((char*)Vs + o), 16, 0, 0);
        }
    };

    stageK(0, 0);  // prologue: 4 loads in flight

    for (int t = 0; t < nt; ++t) {
        int cur = t & 1;
        int kv0 = t * 64;
        stageV(t);                                   // +4
        stageK(cur ^ 1, t + 1 < nt ? t + 1 : t);     // +4
        asm volatile("s_waitcnt vmcnt(8)" ::: "memory");  // K_t landed
        __builtin_amdgcn_sched_barrier(0);
        BAR();

        const char* Kc = (const char*)Ks[cur];
        floatx4 s[2][4] = {};
#pragma unroll
        for (int nm = 0; nm < 4; ++nm)
#pragma unroll
            for (int ks = 0; ks < 4; ++ks) {
                bf16x8 kf = *(const bf16x8*)(Kc + (nm * 16 + l15) * 256 +
                                             ((((ks << 2) | lg) ^ l7) << 4));
                s[0][nm] = __builtin_amdgcn_mfma_f32_16x16x32_bf16(kf, qf[0][ks], s[0][nm], 0, 0, 0);
                s[1][nm] = __builtin_amdgcn_mfma_f32_16x16x32_bf16(kf, qf[1][ks], s[1][nm], 0, 0, 0);
            }

#pragma unroll
        for (int i = 0; i < 2; ++i) {
            if (kv0 + 63 > qbw + i * 16) {
                int qg = qbw + i * 16 + l15;
#pragma unroll
                for (int nm = 0; nm < 4; ++nm)
#pragma unroll
                    for (int r = 0; r < 4; ++r)
                        if (kv0 + nm * 16 + lg4 + r > qg) s[i][nm][r] = -1e30f;
            }
            float pm = -1e30f;
#pragma unroll
            for (int nm = 0; nm < 4; ++nm)
#pragma unroll
                for (int r = 0; r < 4; ++r) pm = fmaxf(pm, s[i][nm][r]);
            pm = fmaxf(pm, __shfl_xor(pm, 16));
            pm = fmaxf(pm, __shfl_xor(pm, 32));
            bool need = !__all(pm - m_run[i] <= 8.f);  // defer-max (T13)
            float corr = 1.f;
            if (need) {
                float mn = fmaxf(m_run[i], pm);
                corr = __expf(m_run[i] - mn);
                m_run[i] = mn;
            }
            float mn = m_run[i];
            float sum = 0.f;
#pragma unroll
            for (int nm = 0; nm < 4; ++nm) {
                bf16x4 pk;
#pragma unroll
                for (int r = 0; r < 4; ++r) {
                    float p = __expf(s[i][nm][r] - mn);
                    sum += p;
                    pk[r] = (bf16)p;
                }
                *(bf16x4*)(Pc + (i * 16 + l15) * 128 +
                           ((((nm << 1) | (lg >> 1)) ^ l7) << 4) + ((lg & 1) << 3)) = pk;
            }
            sum += __shfl_xor(sum, 16);
            sum += __shfl_xor(sum, 32);
            if (need) {
                l_run[i] = l_run[i] * corr + sum;
#pragma unroll
                for (int r = 0; r < 4; ++r) {
                    float cr = __shfl(corr, lg4 + r);
#pragma unroll
                    for (int g = 0; g < 8; ++g) accO[i][g][r] *= cr;
                }
            } else {
                l_run[i] += sum;
            }
        }

        asm volatile("s_waitcnt vmcnt(4)" ::: "memory");  // V_t landed (K_{t+1} in flight)
        __builtin_amdgcn_sched_barrier(0);
        BAR();
        asm volatile("s_waitcnt lgkmcnt(0)" ::: "memory");
        __builtin_amdgcn_sched_barrier(0);

        bf16x8 pf[2][2];
#pragma unroll
        for (int i = 0; i < 2; ++i)
#pragma unroll
            for (int ks = 0; ks < 2; ++ks)
                pf[i][ks] = *(const bf16x8*)(Pc + (i * 16 + l15) * 128 +
                                             ((((ks << 2) | lg) ^ l7) << 4));
#pragma unroll
        for (int g = 0; g < 8; ++g)
#pragma unroll
            for (int ks = 0; ks < 2; ++ks) {
                bf16x8 vf = *(const bf16x8*)((const char*)Vs + (g * 16 + l15) * 128 +
                                             ((((ks << 2) | lg) ^ l7) << 4));
                accO[0][g] = __builtin_amdgcn_mfma_f32_16x16x32_bf16(pf[0][ks], vf, accO[0][g], 0, 0, 0);
                accO[1][g] = __builtin_amdgcn_mfma_f32_16x16x32_bf16(pf[1][ks], vf, accO[1][g], 0, 0, 0);
            }
        BAR();  // Vs WAR: all PV reads done before next stageV lands
    }

#pragma unroll
    for (int i = 0; i < 2; ++i) {
        float inv = 1.f / l_run[i];
#pragma unroll
        for (int r = 0; r < 4; ++r) {
            float vinv = __shfl(inv, lg4 + r);
            int qg = qbw + i * 16 + lg4 + r;
            size_t ob = ((size_t)(b * S_LEN + qg) * NH + h) * HD;
#pragma unroll
            for (int g = 0; g < 8; ++g)
                O[ob + g * 16 + l15] = (bf16)(accO[i][g][r] * vinv);
        }
    }
}

extern "C" void kernel_launch(void* const* d_in, const int* in_sizes, int n_in,
                              void* d_out, int out_size, void* d_ws, size_t ws_size,
                              hipStream_t stream) {
    const float* hs   = (const float*)d_in[0];
    const float* cosp = (const float*)d_in[1];
    const float* sinp = (const float*)d_in[2];
    const float* wqkv = (const float*)d_in[3];
    const float* wo   = (const float*)d_in[4];
    float* out = (float*)d_out;

    char* ws = (char*)d_ws;
    size_t off = 0;
    auto alloc = [&](size_t bytes) {
        char* p = ws + off;
        off += (bytes + 255) & ~(size_t)255;
        return p;
    };
    const size_t n_hs = (size_t)B_DIM * S_LEN * HID;
    const size_t n_wqkv = (size_t)QKVW * HID;
    const size_t n_wo = (size_t)HID * QSZ;
    const size_t n_qkv = (size_t)B_DIM * S_LEN * QKVW;

    bf16* hs_b   = (bf16*)alloc(n_hs * 2);
    bf16* wqkv_b = (bf16*)alloc(n_wqkv * 2);
    bf16* wo_b   = (bf16*)alloc(n_wo * 2);
    bf16* qkv_b  = (bf16*)alloc(n_qkv * 2);
    bf16* Qb  = (bf16*)alloc((size_t)B_DIM * NH * S_LEN * HD * 2);
    bf16* Kb  = (bf16*)alloc((size_t)B_DIM * NKV * S_LEN * HD * 2);
    bf16* Vtb = (bf16*)alloc((size_t)B_DIM * NKV * HD * S_LEN * 2);
    bf16* attn_b = hs_b;  // hs_b dead after gemm1

    cvt_f32_bf16<<<1024, 256, 0, stream>>>(hs, hs_b, (int)n_hs);
    cvt_f32_bf16<<<1024, 256, 0, stream>>>(wqkv, wqkv_b, (int)n_wqkv);
    cvt_f32_bf16<<<1024, 256, 0, stream>>>(wo, wo_b, (int)n_wo);

    gemm256<bf16><<<(4096 / 256) * (6144 / 256), 512, 0, stream>>>(
        hs_b, wqkv_b, qkv_b, B_DIM * S_LEN, QKVW, HID);

    rope_qk<<<B_DIM * S_LEN, 256, 0, stream>>>(qkv_b, cosp, sinp, Qb, Kb);
    v_transpose<<<B_DIM * NKV * (S_LEN / 64) * (HD / 64), 256, 0, stream>>>(qkv_b, Vtb);

    attn_fwd<<<B_DIM * NH * (S_LEN / 128), 256, 0, stream>>>(Qb, Kb, Vtb, attn_b);

    gemm256<float><<<(4096 / 256) * (4096 / 256), 512, 0, stream>>>(
        attn_b, wo_b, out, B_DIM * S_LEN, HID, HID);
}

// Round 5
// 581.814 us; speedup vs baseline: 1.6448x; 1.0147x over previous
//
#include <hip/hip_runtime.h>
#include <hip/hip_bf16.h>
#include <cstdint>

#define B_DIM 2
#define S_LEN 2048
#define HID 4096
#define NH 32
#define NKV 8
#define HD 128
#define QSZ (NH * HD)          // 4096
#define KVSZ (NKV * HD)        // 1024
#define QKVW (QSZ + 2 * KVSZ)  // 6144
#define SCALING 0.08838834764831845f

typedef __bf16 bf16;
typedef __bf16 bf16x4 __attribute__((ext_vector_type(4)));
typedef __bf16 bf16x8 __attribute__((ext_vector_type(8)));
typedef float floatx4 __attribute__((ext_vector_type(4)));

typedef __attribute__((address_space(1))) void GV;
typedef __attribute__((address_space(3))) void SV;

#define BAR() __builtin_amdgcn_s_barrier()
#define SCHED_FENCE() __builtin_amdgcn_sched_barrier(0)

// ---------------- fused f32 -> bf16 convert (3 buffers, 1 launch) ----------------
__global__ __launch_bounds__(256) void cvt3(const float* __restrict__ a, bf16* __restrict__ oa, int na4,
                                            const float* __restrict__ b, bf16* __restrict__ ob, int nb4,
                                            const float* __restrict__ c, bf16* __restrict__ oc, int nc4) {
    int total = na4 + nb4 + nc4;
    int stride = gridDim.x * blockDim.x;
    for (int i = blockIdx.x * blockDim.x + threadIdx.x; i < total; i += stride) {
        const float* src; bf16* dst; int j = i;
        if (j < na4) { src = a; dst = oa; }
        else if ((j -= na4) < nb4) { src = b; dst = ob; }
        else { j -= nb4; src = c; dst = oc; }
        float4 v = ((const float4*)src)[j];
        bf16x4 o;
        o[0] = (bf16)v.x; o[1] = (bf16)v.y; o[2] = (bf16)v.z; o[3] = (bf16)v.w;
        ((bf16x4*)dst)[j] = o;
    }
}

// ---------------- 256x256 8-phase GEMM (for M/256 x N/256 grids that quantize well) ----
template <typename OutT>
__global__ __launch_bounds__(512, 2) void gemm256(const bf16* __restrict__ A,
                                                  const bf16* __restrict__ Bm,
                                                  OutT* __restrict__ C, int M, int N, int K) {
    __shared__ __align__(16) bf16 As[2][2][128 * 64];
    __shared__ __align__(16) bf16 Bs[2][2][128 * 64];
    (void)M;
    int tiles_n = N >> 8;
    int nwg = gridDim.x;
    int bid = blockIdx.x;
    int wg = (bid & 7) * (nwg >> 3) + (bid >> 3);  // XCD chunking
    int st = wg >> 4, within = wg & 15;
    int stn = tiles_n >> 2;
    int bm = (st / stn) * 4 + (within >> 2);
    int bn = (st % stn) * 4 + (within & 3);
    int tid = threadIdx.x;
    int lane = tid & 63, w = tid >> 6;
    int l15 = lane & 15, lg = lane >> 4, l7 = l15 & 7;
    int wm = w >> 2, wn = w & 3;
    const bf16* Ab = A + (size_t)bm * 256 * K;
    const bf16* Bb = Bm + (size_t)bn * 256 * K;

    int o_lo = tid * 16, o_hi = o_lo + 8192;
    int r_lo = o_lo >> 7, r_hi = o_hi >> 7;
    int eo0 = r_lo * K + ((((o_lo >> 4) & 7) ^ (r_lo & 7)) << 3);
    int eo1 = r_hi * K + ((((o_hi >> 4) & 7) ^ (r_hi & 7)) << 3);
    const bf16* AbH[2] = {Ab, Ab + (size_t)128 * K};
    const bf16* BbH[2] = {Bb, Bb + (size_t)128 * K};

    auto stageA = [&](int buf, int h, int kt) {
        const bf16* base = AbH[h] + kt * 64;
        __builtin_amdgcn_global_load_lds((GV*)(base + eo0), (SV*)((char*)As[buf][h] + o_lo), 16, 0, 0);
        __builtin_amdgcn_global_load_lds((GV*)(base + eo1), (SV*)((char*)As[buf][h] + o_hi), 16, 0, 0);
    };
    auto stageB = [&](int buf, int h, int kt) {
        const bf16* base = BbH[h] + kt * 64;
        __builtin_amdgcn_global_load_lds((GV*)(base + eo0), (SV*)((char*)Bs[buf][h] + o_lo), 16, 0, 0);
        __builtin_amdgcn_global_load_lds((GV*)(base + eo1), (SV*)((char*)Bs[buf][h] + o_hi), 16, 0, 0);
    };
    auto rdA = [&](int buf, int fr, int kk) -> bf16x8 {
        int off = (fr * 16 + l15) * 128 + ((((kk << 2) | lg) ^ l7) << 4);
        return *(const bf16x8*)((const char*)As[buf][wm] + off);
    };
    auto rdB = [&](int buf, int fc, int kk) -> bf16x8 {
        int off = ((wn & 1) * 64 + fc * 16 + l15) * 128 + ((((kk << 2) | lg) ^ l7) << 4);
        return *(const bf16x8*)((const char*)Bs[buf][wn >> 1] + off);
    };

    floatx4 acc[8][4] = {};
    bf16x8 aF[4][2], bF[4][2];
    int nk = K >> 6, niter = nk >> 1;

    stageA(0, 0, 0); stageA(0, 1, 0); stageB(0, 0, 0); stageB(0, 1, 0);
    stageB(1, 0, 1); stageB(1, 1, 1);
    asm volatile("s_waitcnt vmcnt(4)" ::: "memory");
    SCHED_FENCE();
    BAR();

    auto quad = [&](int ra, int ca) {
        __builtin_amdgcn_s_setprio(1);
#pragma unroll
        for (int fr = 0; fr < 4; ++fr)
#pragma unroll
            for (int fc = 0; fc < 2; ++fc)
#pragma unroll
                for (int kk = 0; kk < 2; ++kk)
                    acc[ra * 4 + fr][ca * 2 + fc] = __builtin_amdgcn_mfma_f32_16x16x32_bf16(
                        aF[fr][kk], bF[ca * 2 + fc][kk], acc[ra * 4 + fr][ca * 2 + fc], 0, 0, 0);
        __builtin_amdgcn_s_setprio(0);
    };

    for (int i = 0; i < niter; ++i) {
        bool nl = (i + 1 < niter);
        int kt1 = 2 * i + 1, kt2 = 2 * i + 2, kt3 = 2 * i + 3;
        // P0
#pragma unroll
        for (int fr = 0; fr < 4; ++fr)
#pragma unroll
            for (int kk = 0; kk < 2; ++kk) aF[fr][kk] = rdA(0, fr, kk);
#pragma unroll
        for (int fc = 0; fc < 2; ++fc)
#pragma unroll
            for (int kk = 0; kk < 2; ++kk) bF[fc][kk] = rdB(0, fc, kk);
        stageA(1, 0, kt1);
        BAR(); quad(0, 0); BAR();
        // P1
#pragma unroll
        for (int fc = 2; fc < 4; ++fc)
#pragma unroll
            for (int kk = 0; kk < 2; ++kk) bF[fc][kk] = rdB(0, fc, kk);
        stageA(1, 1, kt1);
        BAR(); quad(0, 1); BAR();
        // P2
#pragma unroll
        for (int fr = 0; fr < 4; ++fr)
#pragma unroll
            for (int kk = 0; kk < 2; ++kk) aF[fr][kk] = rdA(0, 4 + fr, kk);
        if (nl) stageB(0, 0, kt2);
        BAR(); quad(1, 0); BAR();
        // P3
        if (nl) stageB(0, 1, kt2);
        BAR(); quad(1, 1);
        if (nl) asm volatile("s_waitcnt vmcnt(4)" ::: "memory");
        else    asm volatile("s_waitcnt vmcnt(0)" ::: "memory");
        SCHED_FENCE();
        BAR();
        // P4
#pragma unroll
        for (int fr = 0; fr < 4; ++fr)
#pragma unroll
            for (int kk = 0; kk < 2; ++kk) aF[fr][kk] = rdA(1, fr, kk);
#pragma unroll
        for (int fc = 0; fc < 2; ++fc)
#pragma unroll
            for (int kk = 0; kk < 2; ++kk) bF[fc][kk] = rdB(1, fc, kk);
        if (nl) stageA(0, 0, kt2);
        BAR(); quad(0, 0); BAR();
        // P5
#pragma unroll
        for (int fc = 2; fc < 4; ++fc)
#pragma unroll
            for (int kk = 0; kk < 2; ++kk) bF[fc][kk] = rdB(1, fc, kk);
        if (nl) stageA(0, 1, kt2);
        BAR(); quad(0, 1); BAR();
        // P6
#pragma unroll
        for (int fr = 0; fr < 4; ++fr)
#pragma unroll
            for (int kk = 0; kk < 2; ++kk) aF[fr][kk] = rdA(1, 4 + fr, kk);
        if (nl) stageB(1, 0, kt3);
        BAR(); quad(1, 0); BAR();
        // P7
        if (nl) stageB(1, 1, kt3);
        BAR(); quad(1, 1);
        asm volatile("s_waitcnt vmcnt(4)" ::: "memory");
        SCHED_FENCE();
        BAR();
    }

    int brow = bm * 256 + wm * 128, bcol = bn * 256 + wn * 64;
#pragma unroll
    for (int fr = 0; fr < 8; ++fr)
#pragma unroll
        for (int fc = 0; fc < 4; ++fc) {
            int col = bcol + fc * 16 + l15;
#pragma unroll
            for (int r = 0; r < 4; ++r) {
                int row = brow + fr * 16 + lg * 4 + r;
                C[(size_t)row * N + col] = (OutT)acc[fr][fc][r];
            }
        }
}

// ---------------- 128x256 GEMM (grid quantization for M=4096, N=6144: 768 blocks = 3.0 rounds)
// 512 thr = 8 waves (2Mx4N), per-wave 64x64 out, BK=64, 2 phases per K-tile.
// LDS 96 KB: As 2x16KB, Bs 2x32KB. Staging 2 K-tiles deep, vmcnt(6) per K-tile.
template <typename OutT>
__global__ __launch_bounds__(512, 2) void gemm128(const bf16* __restrict__ A,
                                                  const bf16* __restrict__ Bm,
                                                  OutT* __restrict__ C, int M, int N, int K) {
    __shared__ __align__(16) bf16 As[2][128 * 64];
    __shared__ __align__(16) bf16 Bs[2][2][128 * 64];
    (void)M;
    int tiles_n = N >> 8;  // 256-wide
    int nwg = gridDim.x;
    int bid = blockIdx.x;
    int wg = (bid & 7) * (nwg >> 3) + (bid >> 3);  // XCD chunking (nwg%8==0)
    int st = wg >> 4, within = wg & 15;            // 4x4 supertiles
    int stn = tiles_n >> 2;
    int bm = (st / stn) * 4 + (within >> 2);
    int bn = (st % stn) * 4 + (within & 3);
    int tid = threadIdx.x;
    int lane = tid & 63, w = tid >> 6;
    int l15 = lane & 15, lg = lane >> 4, l7 = l15 & 7;
    int wm = w >> 2, wn = w & 3;
    const bf16* Ab = A + (size_t)bm * 128 * K;
    const bf16* Bb = Bm + (size_t)bn * 256 * K;

    int o_lo = tid * 16, o_hi = o_lo + 8192;
    int r_lo = o_lo >> 7, r_hi = o_hi >> 7;
    int eo0 = r_lo * K + ((((o_lo >> 4) & 7) ^ (r_lo & 7)) << 3);
    int eo1 = r_hi * K + ((((o_hi >> 4) & 7) ^ (r_hi & 7)) << 3);
    const bf16* BbH[2] = {Bb, Bb + (size_t)128 * K};

    auto stageA = [&](int buf, int kt) {
        const bf16* base = Ab + kt * 64;
        __builtin_amdgcn_global_load_lds((GV*)(base + eo0), (SV*)((char*)As[buf] + o_lo), 16, 0, 0);
        __builtin_amdgcn_global_load_lds((GV*)(base + eo1), (SV*)((char*)As[buf] + o_hi), 16, 0, 0);
    };
    auto stageB = [&](int buf, int h, int kt) {
        const bf16* base = BbH[h] + kt * 64;
        __builtin_amdgcn_global_load_lds((GV*)(base + eo0), (SV*)((char*)Bs[buf][h] + o_lo), 16, 0, 0);
        __builtin_amdgcn_global_load_lds((GV*)(base + eo1), (SV*)((char*)Bs[buf][h] + o_hi), 16, 0, 0);
    };
    auto rdA = [&](int buf, int fr, int kk) -> bf16x8 {
        int row = wm * 64 + fr * 16 + l15;
        int off = row * 128 + ((((kk << 2) | lg) ^ l7) << 4);
        return *(const bf16x8*)((const char*)As[buf] + off);
    };
    auto rdB = [&](int buf, int fc, int kk) -> bf16x8 {
        int off = ((wn & 1) * 64 + fc * 16 + l15) * 128 + ((((kk << 2) | lg) ^ l7) << 4);
        return *(const bf16x8*)((const char*)Bs[buf][wn >> 1] + off);
    };

    floatx4 acc[4][4] = {};
    bf16x8 aF[4][2], bF[4][2];
    int nk = K >> 6;

    // prologue: kt0 -> dbuf0 (6), kt1 -> dbuf1 (6); wait kt0
    stageA(0, 0); stageB(0, 0, 0); stageB(0, 1, 0);
    stageA(1, 1); stageB(1, 0, 1); stageB(1, 1, 1);
    asm volatile("s_waitcnt vmcnt(6)" ::: "memory");
    SCHED_FENCE();
    BAR();

    auto quad = [&](int ca) {
        __builtin_amdgcn_s_setprio(1);
#pragma unroll
        for (int fr = 0; fr < 4; ++fr)
#pragma unroll
            for (int f2 = 0; f2 < 2; ++f2)
#pragma unroll
                for (int kk = 0; kk < 2; ++kk)
                    acc[fr][ca * 2 + f2] = __builtin_amdgcn_mfma_f32_16x16x32_bf16(
                        aF[fr][kk], bF[ca * 2 + f2][kk], acc[fr][ca * 2 + f2], 0, 0, 0);
        __builtin_amdgcn_s_setprio(0);
    };

    for (int kt = 0; kt < nk; ++kt) {
        int cur = kt & 1;
        bool deep = (kt + 2 < nk);
        // ---- P0: read aF + bF[0..1] from dbuf[cur]
#pragma unroll
        for (int fr = 0; fr < 4; ++fr)
#pragma unroll
            for (int kk = 0; kk < 2; ++kk) aF[fr][kk] = rdA(cur, fr, kk);
#pragma unroll
        for (int fc = 0; fc < 2; ++fc)
#pragma unroll
            for (int kk = 0; kk < 2; ++kk) bF[fc][kk] = rdB(cur, fc, kk);
        BAR();
        quad(0);
        BAR();
        // ---- P1: read bF[2..3]; then (after barrier) stage kt+2 -> dbuf[cur]
#pragma unroll
        for (int fc = 2; fc < 4; ++fc)
#pragma unroll
            for (int kk = 0; kk < 2; ++kk) bF[fc][kk] = rdB(cur, fc, kk);
        SCHED_FENCE();  // keep reads above the barrier
        BAR();
        SCHED_FENCE();  // keep stage issue below the barrier (WAR on dbuf[cur])
        if (deep) { stageA(cur, kt + 2); stageB(cur, 0, kt + 2); stageB(cur, 1, kt + 2); }
        quad(1);
        if (deep) asm volatile("s_waitcnt vmcnt(6)" ::: "memory");
        else      asm volatile("s_waitcnt vmcnt(0)" ::: "memory");
        SCHED_FENCE();
        BAR();
    }

    int brow = bm * 128 + wm * 64, bcol = bn * 256 + wn * 64;
#pragma unroll
    for (int fr = 0; fr < 4; ++fr)
#pragma unroll
        for (int fc = 0; fc < 4; ++fc) {
            int col = bcol + fc * 16 + l15;
#pragma unroll
            for (int r = 0; r < 4; ++r) {
                int row = brow + fr * 16 + lg * 4 + r;
                C[(size_t)row * N + col] = (OutT)acc[fr][fc][r];
            }
        }
}

// ---------------- RoPE + reshape (Q pre-scaled by SCALING) ----------------
__global__ __launch_bounds__(256) void rope_qk(const bf16* __restrict__ qkv,
                                               const float* __restrict__ cosp,
                                               const float* __restrict__ sinp,
                                               bf16* __restrict__ Q, bf16* __restrict__ K) {
    int bs = blockIdx.x;
    int b = bs >> 11, s = bs & (S_LEN - 1);
    const bf16* row = qkv + (size_t)bs * QKVW;
    const float* cr = cosp + (size_t)bs * HD;
    const float* sr = sinp + (size_t)bs * HD;
    int t = threadIdx.x;
    int h = t >> 3, d0 = (t & 7) * 8;
    {
        bf16x8 x1 = *(const bf16x8*)(row + h * HD + d0);
        bf16x8 x2 = *(const bf16x8*)(row + h * HD + 64 + d0);
        bf16x8 o1, o2;
#pragma unroll
        for (int j = 0; j < 8; ++j) {
            float a = (float)x1[j], bv = (float)x2[j];
            o1[j] = (bf16)((a * cr[d0 + j] - bv * sr[d0 + j]) * SCALING);
            o2[j] = (bf16)((bv * cr[64 + d0 + j] + a * sr[64 + d0 + j]) * SCALING);
        }
        size_t qb = (((size_t)b * NH + h) * S_LEN + s) * HD;
        *(bf16x8*)(Q + qb + d0) = o1;
        *(bf16x8*)(Q + qb + 64 + d0) = o2;
    }
    if (t < 64) {
        int kh = t >> 3;
        bf16x8 x1 = *(const bf16x8*)(row + QSZ + kh * HD + d0);
        bf16x8 x2 = *(const bf16x8*)(row + QSZ + kh * HD + 64 + d0);
        bf16x8 o1, o2;
#pragma unroll
        for (int j = 0; j < 8; ++j) {
            float a = (float)x1[j], bv = (float)x2[j];
            o1[j] = (bf16)(a * cr[d0 + j] - bv * sr[d0 + j]);
            o2[j] = (bf16)(bv * cr[64 + d0 + j] + a * sr[64 + d0 + j]);
        }
        size_t kb = (((size_t)b * NKV + kh) * S_LEN + s) * HD;
        *(bf16x8*)(K + kb + d0) = o1;
        *(bf16x8*)(K + kb + 64 + d0) = o2;
    }
}

// ---------------- V transpose: qkv v-slice -> Vt[B,NKV,HD,S] ----------------
__global__ __launch_bounds__(256) void v_transpose(const bf16* __restrict__ qkv,
                                                   bf16* __restrict__ Vt) {
    int bid = blockIdx.x;
    int dt = bid & 1, st = (bid >> 1) & 31, bk = bid >> 6;
    int b = bk >> 3, kv = bk & 7;
    __shared__ __align__(16) bf16 tile[64][72];
    int t = threadIdx.x;
#pragma unroll
    for (int it = 0; it < 2; ++it) {
        int i = it * 32 + (t >> 3);
        int j8 = (t & 7) * 8;
        bf16x8 v = *(const bf16x8*)(qkv + ((size_t)(b * S_LEN + st * 64 + i)) * QKVW +
                                    QSZ + KVSZ + kv * HD + dt * 64 + j8);
        *(bf16x8*)&tile[i][j8] = v;
    }
    __syncthreads();
    int dl = t >> 2, s8 = (t & 3) * 16;
    bf16x8 o0, o1;
#pragma unroll
    for (int u = 0; u < 8; ++u) { o0[u] = tile[s8 + u][dl]; o1[u] = tile[s8 + 8 + u][dl]; }
    size_t ob = (((size_t)b * NKV + kv) * HD + dt * 64 + dl) * S_LEN + st * 64 + s8;
    *(bf16x8*)(Vt + ob) = o0;
    *(bf16x8*)(Vt + ob + 8) = o1;
}

// ---------------- causal GQA flash attention ----------------
__global__ __launch_bounds__(256, 2) void attn_fwd(const bf16* __restrict__ Q,
                                                   const bf16* __restrict__ K,
                                                   const bf16* __restrict__ Vt,
                                                   bf16* __restrict__ O) {
    __shared__ __align__(16) bf16 Ks[2][64 * 128];
    __shared__ __align__(16) bf16 Vs[128 * 64];
    __shared__ __align__(16) bf16 Ps[4][32 * 64];

    int nwg = gridDim.x;
    int bid0 = blockIdx.x;
    int bid = (bid0 & 7) * (nwg >> 3) + (bid0 >> 3);
    int qt = bid & 15, bh = bid >> 4, h = bh & 31, b = bh >> 5;
    int kvh = h >> 2;
    int tid = threadIdx.x, lane = tid & 63, w = tid >> 6;
    int l15 = lane & 15, lg = lane >> 4, l7 = l15 & 7, lg4 = lg * 4;
    int q0 = qt * 128;
    int qbw = q0 + w * 32;

    const bf16* Qb = Q + ((size_t)(b * NH + h) * S_LEN) * HD;
    const bf16* Kb = K + ((size_t)(b * NKV + kvh) * S_LEN) * HD;
    const bf16* Vb = Vt + ((size_t)(b * NKV + kvh) * HD) * S_LEN;

    bf16x8 qf[2][4];
#pragma unroll
    for (int i = 0; i < 2; ++i)
#pragma unroll
        for (int ks = 0; ks < 4; ++ks)
            qf[i][ks] = *(const bf16x8*)(Qb + (size_t)(qbw + i * 16 + l15) * HD + ks * 32 + lg * 8);

    floatx4 accO[2][8] = {};
    float m_run[2] = {-1e30f, -1e30f}, l_run[2] = {0.f, 0.f};

    char* Pc = (char*)Ps[w];
    int nt = 2 * qt + 2;

    auto stageK = [&](int buf, int t) {
        int kv0 = t * 64;
#pragma unroll
        for (int it = 0; it < 4; ++it) {
            int o = it * 4096 + tid * 16;
            int r = o >> 8, pb = (o >> 4) & 15;
            int lb = pb ^ (r & 7);
            __builtin_amdgcn_global_load_lds((GV*)(Kb + (size_t)(kv0 + r) * HD + lb * 8),
                                             (SV*)((char*)Ks[buf] + o), 16, 0, 0);
        }
    };
    auto stageV = [&](int t) {
        int kv0 = t * 64;
#pragma unroll
        for (int it = 0; it < 4; ++it) {
            int o = it * 4096 + tid * 16;
            int d = o >> 7, pb = (o >> 4) & 7;
            int lb = pb ^ (d & 7);
            __builtin_amdgcn_global_load_lds((GV*)(Vb + (size_t)d * S_LEN + kv0 + lb * 8),
                                             (SV*)((char*)Vs + o), 16, 0, 0);
        }
    };

    stageK(0, 0);

    for (int t = 0; t < nt; ++t) {
        int cur = t & 1;
        int kv0 = t * 64;
        stageV(t);
        stageK(cur ^ 1, t + 1 < nt ? t + 1 : t);
        asm volatile("s_waitcnt vmcnt(8)" ::: "memory");
        SCHED_FENCE();
        BAR();

        const char* Kc = (const char*)Ks[cur];
        floatx4 s[2][4] = {};
#pragma unroll
        for (int nm = 0; nm < 4; ++nm)
#pragma unroll
            for (int ks = 0; ks < 4; ++ks) {
                bf16x8 kf = *(const bf16x8*)(Kc + (nm * 16 + l15) * 256 +
                                             ((((ks << 2) | lg) ^ l7) << 4));
                s[0][nm] = __builtin_amdgcn_mfma_f32_16x16x32_bf16(kf, qf[0][ks], s[0][nm], 0, 0, 0);
                s[1][nm] = __builtin_amdgcn_mfma_f32_16x16x32_bf16(kf, qf[1][ks], s[1][nm], 0, 0, 0);
            }

#pragma unroll
        for (int i = 0; i < 2; ++i) {
            if (kv0 + 63 > qbw + i * 16) {
                int qg = qbw + i * 16 + l15;
#pragma unroll
                for (int nm = 0; nm < 4; ++nm)
#pragma unroll
                    for (int r = 0; r < 4; ++r)
                        if (kv0 + nm * 16 + lg4 + r > qg) s[i][nm][r] = -1e30f;
            }
            float pm = -1e30f;
#pragma unroll
            for (int nm = 0; nm < 4; ++nm)
#pragma unroll
                for (int r = 0; r < 4; ++r) pm = fmaxf(pm, s[i][nm][r]);
            pm = fmaxf(pm, __shfl_xor(pm, 16));
            pm = fmaxf(pm, __shfl_xor(pm, 32));
            bool need = !__all(pm - m_run[i] <= 8.f);
            float corr = 1.f;
            if (need) {
                float mn = fmaxf(m_run[i], pm);
                corr = __expf(m_run[i] - mn);
                m_run[i] = mn;
            }
            float mn = m_run[i];
            float sum = 0.f;
#pragma unroll
            for (int nm = 0; nm < 4; ++nm) {
                bf16x4 pk;
#pragma unroll
                for (int r = 0; r < 4; ++r) {
                    float p = __expf(s[i][nm][r] - mn);
                    sum += p;
                    pk[r] = (bf16)p;
                }
                *(bf16x4*)(Pc + (i * 16 + l15) * 128 +
                           ((((nm << 1) | (lg >> 1)) ^ l7) << 4) + ((lg & 1) << 3)) = pk;
            }
            sum += __shfl_xor(sum, 16);
            sum += __shfl_xor(sum, 32);
            if (need) {
                l_run[i] = l_run[i] * corr + sum;
#pragma unroll
                for (int r = 0; r < 4; ++r) {
                    float cr = __shfl(corr, lg4 + r);
#pragma unroll
                    for (int g = 0; g < 8; ++g) accO[i][g][r] *= cr;
                }
            } else {
                l_run[i] += sum;
            }
        }

        asm volatile("s_waitcnt vmcnt(4)" ::: "memory");
        SCHED_FENCE();
        BAR();
        asm volatile("s_waitcnt lgkmcnt(0)" ::: "memory");
        SCHED_FENCE();

        bf16x8 pf[2][2];
#pragma unroll
        for (int i = 0; i < 2; ++i)
#pragma unroll
            for (int ks = 0; ks < 2; ++ks)
                pf[i][ks] = *(const bf16x8*)(Pc + (i * 16 + l15) * 128 +
                                             ((((ks << 2) | lg) ^ l7) << 4));
#pragma unroll
        for (int g = 0; g < 8; ++g)
#pragma unroll
            for (int ks = 0; ks < 2; ++ks) {
                bf16x8 vf = *(const bf16x8*)((const char*)Vs + (g * 16 + l15) * 128 +
                                             ((((ks << 2) | lg) ^ l7) << 4));
                accO[0][g] = __builtin_amdgcn_mfma_f32_16x16x32_bf16(pf[0][ks], vf, accO[0][g], 0, 0, 0);
                accO[1][g] = __builtin_amdgcn_mfma_f32_16x16x32_bf16(pf[1][ks], vf, accO[1][g], 0, 0, 0);
            }
        BAR();
    }

#pragma unroll
    for (int i = 0; i < 2; ++i) {
        float inv = 1.f / l_run[i];
#pragma unroll
        for (int r = 0; r < 4; ++r) {
            float vinv = __shfl(inv, lg4 + r);
            int qg = qbw + i * 16 + lg4 + r;
            size_t ob = ((size_t)(b * S_LEN + qg) * NH + h) * HD;
#pragma unroll
            for (int g = 0; g < 8; ++g)
                O[ob + g * 16 + l15] = (bf16)(accO[i][g][r] * vinv);
        }
    }
}

extern "C" void kernel_launch(void* const* d_in, const int* in_sizes, int n_in,
                              void* d_out, int out_size, void* d_ws, size_t ws_size,
                              hipStream_t stream) {
    const float* hs   = (const float*)d_in[0];
    const float* cosp = (const float*)d_in[1];
    const float* sinp = (const float*)d_in[2];
    const float* wqkv = (const float*)d_in[3];
    const float* wo   = (const float*)d_in[4];
    float* out = (float*)d_out;

    char* ws = (char*)d_ws;
    size_t off = 0;
    auto alloc = [&](size_t bytes) {
        char* p = ws + off;
        off += (bytes + 255) & ~(size_t)255;
        return p;
    };
    const size_t n_hs = (size_t)B_DIM * S_LEN * HID;
    const size_t n_wqkv = (size_t)QKVW * HID;
    const size_t n_wo = (size_t)HID * QSZ;
    const size_t n_qkv = (size_t)B_DIM * S_LEN * QKVW;

    bf16* hs_b   = (bf16*)alloc(n_hs * 2);
    bf16* wqkv_b = (bf16*)alloc(n_wqkv * 2);
    bf16* wo_b   = (bf16*)alloc(n_wo * 2);
    bf16* qkv_b  = (bf16*)alloc(n_qkv * 2);
    bf16* Qb  = (bf16*)alloc((size_t)B_DIM * NH * S_LEN * HD * 2);
    bf16* Kb  = (bf16*)alloc((size_t)B_DIM * NKV * S_LEN * HD * 2);
    bf16* Vtb = (bf16*)alloc((size_t)B_DIM * NKV * HD * S_LEN * 2);
    bf16* attn_b = hs_b;  // hs_b dead after gemm1

    cvt3<<<2048, 256, 0, stream>>>(hs, hs_b, (int)(n_hs >> 2),
                                   wqkv, wqkv_b, (int)(n_wqkv >> 2),
                                   wo, wo_b, (int)(n_wo >> 2));

    gemm128<bf16><<<(4096 / 128) * (6144 / 256), 512, 0, stream>>>(
        hs_b, wqkv_b, qkv_b, B_DIM * S_LEN, QKVW, HID);

    rope_qk<<<B_DIM * S_LEN, 256, 0, stream>>>(qkv_b, cosp, sinp, Qb, Kb);
    v_transpose<<<B_DIM * NKV * (S_LEN / 64) * (HD / 64), 256, 0, stream>>>(qkv_b, Vtb);

    attn_fwd<<<B_DIM * NH * (S_LEN / 128), 256, 0, stream>>>(Qb, Kb, Vtb, attn_b);

    gemm256<float><<<(4096 / 256) * (4096 / 256), 512, 0, stream>>>(
        attn_b, wo_b, out, B_DIM * S_LEN, HID, HID);
}